// Round 8
// baseline (905.326 us; speedup 1.0000x reference)
//
#include <hip/hip_runtime.h>

#define N_NODES 100000
#define N_EDGES 1600000
#define D 128
#define NLAYER 3
#define NSLOT 32

// bucket sort params
#define NBKT 98          // ceil(100000 / 1024) node-buckets of 1024
#define EPB 4096         // edges per block in phase A
#define BCAP 96          // LDS per-bucket capacity (mean ~42/block)

typedef __bf16 bf16x8 __attribute__((ext_vector_type(8)));
typedef float f32x4 __attribute__((ext_vector_type(4)));

__device__ inline ushort f2b(float f) {
    union { float f; unsigned u; } v; v.f = f;
    unsigned u = v.u;
    return (ushort)((u + 0x7FFFu + ((u >> 16) & 1u)) >> 16);  // RNE
}
__device__ inline float b2f_lo(unsigned u) {
    union { unsigned u; float f; } v; v.u = u << 16; return v.f;
}
__device__ inline float b2f_hi(unsigned u) {
    union { unsigned u; float f; } v; v.u = u & 0xFFFF0000u; return v.f;
}

// x fp32 -> packed bf16 (layer-0 agg input): halves layer-0 gather bytes
__global__ __launch_bounds__(256)
void k_x2b(const float* __restrict__ x, unsigned* __restrict__ out, int n4) {
    int i = blockIdx.x * 256 + threadIdx.x;  // float4 index
    if (i >= n4) return;
    float4 v = ((const float4*)x)[i];
    uint2 o;
    o.x = (unsigned)f2b(v.x) | ((unsigned)f2b(v.y) << 16);
    o.y = (unsigned)f2b(v.z) | ((unsigned)f2b(v.w) << 16);
    ((uint2*)out)[i] = o;
}

// ---------------------------------------------------------------- CSR build
// Histogram kept as its OWN kernel: 6250 blocks hide the 1.6M random atomic
// latencies (fusing it into k_bucket's 391-block grid was a 2.4x regression).
__global__ void k_hist(const int* __restrict__ dst, int* __restrict__ deg, int e) {
    int i = blockIdx.x * blockDim.x + threadIdx.x;
    if (i < e) atomicAdd(&deg[dst[i]], 1);
}

__global__ void k_scan_partial(const int* __restrict__ deg, int* __restrict__ bsum, int n) {
    __shared__ int sd[256];
    int tid  = threadIdx.x;
    int base = blockIdx.x * 1024 + tid * 4;
    int s = 0;
    #pragma unroll
    for (int j = 0; j < 4; ++j) {
        int idx = base + j;
        if (idx < n) s += deg[idx];
    }
    sd[tid] = s;
    __syncthreads();
    for (int o = 128; o > 0; o >>= 1) {
        if (tid < o) sd[tid] += sd[tid + o];
        __syncthreads();
    }
    if (tid == 0) bsum[blockIdx.x] = sd[0];
}

__global__ void k_scan_top(int* __restrict__ bsum, int nb) {
    __shared__ int sd[128];
    int tid = threadIdx.x;
    int v = (tid < nb) ? bsum[tid] : 0;
    sd[tid] = v;
    __syncthreads();
    int tot = v;
    for (int o = 1; o < 128; o <<= 1) {
        int t = (tid >= o) ? sd[tid - o] : 0;
        __syncthreads();
        sd[tid] += t;
        __syncthreads();
    }
    if (tid < nb) bsum[tid] = sd[tid] - tot;  // exclusive
}

__global__ void k_scan_final(const int* __restrict__ deg, const int* __restrict__ bofs,
                             int* __restrict__ offs, int* __restrict__ cursor,
                             int* __restrict__ bcur, int n) {
    __shared__ int sd[256];
    int tid  = threadIdx.x;
    int base = blockIdx.x * 1024 + tid * 4;
    int v[4];
    int s = 0;
    #pragma unroll
    for (int j = 0; j < 4; ++j) {
        int idx = base + j;
        v[j] = (idx < n) ? deg[idx] : 0;
        s += v[j];
    }
    sd[tid] = s;
    __syncthreads();
    int own = s;
    for (int o = 1; o < 256; o <<= 1) {
        int t = (tid >= o) ? sd[tid - o] : 0;
        __syncthreads();
        sd[tid] += t;
        __syncthreads();
    }
    int excl = sd[tid] - own + bofs[blockIdx.x];
    #pragma unroll
    for (int j = 0; j < 4; ++j) {
        int idx = base + j;
        if (idx < n) {
            offs[idx] = excl; cursor[idx] = excl;
            if ((idx & 1023) == 0) bcur[idx >> 10] = excl;  // bucket region start
        }
        excl += v[j];
    }
}

// ---------------------------------------------------------------- bucketed edge sort
__global__ __launch_bounds__(256)
void k_bucket(const int* __restrict__ src, const int* __restrict__ dst,
              int* __restrict__ bcur, unsigned* __restrict__ staged, int e) {
    __shared__ unsigned lstage[NBKT * BCAP];
    __shared__ int lcur[NBKT];
    __shared__ int lbase[NBKT];
    int tid = threadIdx.x;
    for (int b = tid; b < NBKT; b += 256) lcur[b] = 0;
    __syncthreads();
    int base = blockIdx.x * EPB;
    for (int k = 0; k < EPB / 256; ++k) {
        int eid = base + k * 256 + tid;
        if (eid < e) {
            int d = dst[eid];
            int s = src[eid];
            int b = d >> 10;
            unsigned packed = ((unsigned)(d & 1023) << 17) | (unsigned)s;
            int p = atomicAdd(&lcur[b], 1);
            if (p < BCAP) {
                lstage[b * BCAP + p] = packed;
            } else {  // overflow fallback (statistically never: cap = 2.3x mean)
                int gp = atomicAdd(&bcur[b], 1);
                staged[gp] = packed;
            }
        }
    }
    __syncthreads();
    if (tid < NBKT) {
        int cnt = min(lcur[tid], BCAP);
        lbase[tid] = atomicAdd(&bcur[tid], cnt);
        lcur[tid] = cnt;
    }
    __syncthreads();
    int wave = tid >> 6, lane = tid & 63;
    for (int b = wave; b < NBKT; b += 4) {
        int cnt = lcur[b], gb = lbase[b];
        for (int j = lane; j < cnt; j += 64)
            staged[gb + j] = lstage[b * BCAP + j];
    }
}

__global__ __launch_bounds__(1024)
void k_place(const unsigned* __restrict__ staged, const int* __restrict__ offs,
             int* __restrict__ cursor, int* __restrict__ csrc) {
    int b = blockIdx.x;
    int start = offs[b << 10];
    int end = (b == NBKT - 1) ? N_EDGES : offs[(b + 1) << 10];
    int nodebase = b << 10;
    for (int i = start + blockIdx.y * 1024 + threadIdx.x; i < end; i += 2048) {
        unsigned p = staged[i];
        int s = (int)(p & 0x1FFFFu);
        int rel = (int)(p >> 17);
        int pos = atomicAdd(&cursor[nodebase + rel], 1);
        csrc[pos] = s;
    }
}

// ---------------------------------------------------------------- aggregation
// out[i,:] = bf16( f(h[i,:]) + sum_j f(h[src_j,:]) ),  f = AFF ? relu(v*sc+sh) : v.
// One wave per node (25000 blocks -> full gather TLP; do NOT fuse with GEMM).
template <bool AFF>
__device__ inline void acc8(float* a, uint4 u, const float* sc, const float* sh) {
    float v[8];
    v[0] = b2f_lo(u.x); v[1] = b2f_hi(u.x);
    v[2] = b2f_lo(u.y); v[3] = b2f_hi(u.y);
    v[4] = b2f_lo(u.z); v[5] = b2f_hi(u.z);
    v[6] = b2f_lo(u.w); v[7] = b2f_hi(u.w);
    #pragma unroll
    for (int j = 0; j < 8; ++j) {
        float t = v[j];
        if (AFF) {
            t = t * sc[j] + sh[j];
            t = t > 0.f ? t : 0.f;
        }
        a[j] += t;
    }
}

template <bool AFF>
__global__ __launch_bounds__(256)
void k_agg(const unsigned* __restrict__ h, const int* __restrict__ offs,
           const int* __restrict__ deg, const int* __restrict__ csrc,
           const float* __restrict__ sc_, const float* __restrict__ sh_,
           unsigned* __restrict__ out, int n) {
    int node = blockIdx.x * 4 + (threadIdx.x >> 6);
    if (node >= n) return;
    int lane = threadIdx.x & 63;
    int q  = lane >> 4;   // neighbor stream j === q (mod 4)
    int sl = lane & 15;   // covers uints 4sl..4sl+3 (cols 8sl..8sl+7)
    const uint4* hp = (const uint4*)h;
    float sc[8], sh[8];
    if (AFF) {
        #pragma unroll
        for (int j = 0; j < 8; ++j) { sc[j] = sc_[sl * 8 + j]; sh[j] = sh_[sl * 8 + j]; }
    }
    float a[8];
    #pragma unroll
    for (int j = 0; j < 8; ++j) a[j] = 0.f;
    if (q == 0) acc8<AFF>(a, hp[(size_t)node * 16 + sl], sc, sh);
    int s = offs[node], d = deg[node];
    for (int c = 0; c < d; c += 64) {
        int m = min(64, d - c);
        int myi = (lane < m) ? csrc[s + c + lane] : 0;
        int g4 = m >> 2;
        int g = 0;
        for (; g + 4 <= g4; g += 4) {
            int n0 = __shfl(myi, 4 * g + 0 + q);
            int n1 = __shfl(myi, 4 * g + 4 + q);
            int n2 = __shfl(myi, 4 * g + 8 + q);
            int n3 = __shfl(myi, 4 * g + 12 + q);
            uint4 u0 = hp[(size_t)n0 * 16 + sl];
            uint4 u1 = hp[(size_t)n1 * 16 + sl];
            uint4 u2 = hp[(size_t)n2 * 16 + sl];
            uint4 u3 = hp[(size_t)n3 * 16 + sl];
            acc8<AFF>(a, u0, sc, sh);
            acc8<AFF>(a, u1, sc, sh);
            acc8<AFF>(a, u2, sc, sh);
            acc8<AFF>(a, u3, sc, sh);
        }
        for (; g < g4; ++g) {
            int nb = __shfl(myi, 4 * g + q);
            acc8<AFF>(a, hp[(size_t)nb * 16 + sl], sc, sh);
        }
        int rem = m & 3;
        if (rem) {
            int j = 4 * g4 + q;
            int nb = __shfl(myi, j < m ? j : 0);  // convergent shfl
            if (q < rem) acc8<AFF>(a, hp[(size_t)nb * 16 + sl], sc, sh);
        }
    }
    #pragma unroll
    for (int j = 0; j < 8; ++j) {
        a[j] += __shfl_xor(a[j], 16);
        a[j] += __shfl_xor(a[j], 32);
    }
    if (q == 0) {
        uint4 o;
        o.x = (unsigned)f2b(a[0]) | ((unsigned)f2b(a[1]) << 16);
        o.y = (unsigned)f2b(a[2]) | ((unsigned)f2b(a[3]) << 16);
        o.z = (unsigned)f2b(a[4]) | ((unsigned)f2b(a[5]) << 16);
        o.w = (unsigned)f2b(a[6]) | ((unsigned)f2b(a[7]) << 16);
        ((uint4*)out)[(size_t)node * 16 + sl] = o;
    }
}

// ---------------------------------------------------------------- weight prep
// Both W1,W2 fp32 [3][k][n] -> transposed bf16 [3][n][k] in ONE launch (z picks).
__global__ void k_wprep(const float* __restrict__ W1, const float* __restrict__ W2,
                        ushort* __restrict__ Wt1, ushort* __restrict__ Wt2) {
    int m = blockIdx.y, nn = blockIdx.x, k = threadIdx.x;
    const float* W = blockIdx.z ? W2 : W1;
    ushort* Wt = blockIdx.z ? Wt2 : Wt1;
    Wt[(m * D + nn) * D + k] = f2b(W[(m * D + k) * D + nn]);
}

// ---------------------------------------------------------------- MFMA GEMM
// AFF=false: C = A @ Wt + bias          (A raw bf16)
// AFF=true : C = relu(bn(A)) @ Wt + bias, bn params computed in prologue from
//            stats_in.  If scale_out != nullptr, the LAST block (atomic ticket)
//            also folds stats_out -> scale_out/shift_out (deletes k_bnparams
//            from the critical path; no block ever WAITS on the ticket, so no
//            deadlock is possible).
__device__ inline bf16x8 affine_frag(uint4 raw, int kb,
                                     const float* __restrict__ sc,
                                     const float* __restrict__ sh) {
    unsigned u[4];
    u[0] = raw.x; u[1] = raw.y; u[2] = raw.z; u[3] = raw.w;
    bf16x8 r;
    #pragma unroll
    for (int p = 0; p < 4; ++p) {
        float lo = b2f_lo(u[p]) * sc[kb + 2 * p] + sh[kb + 2 * p];
        float hi = b2f_hi(u[p]) * sc[kb + 2 * p + 1] + sh[kb + 2 * p + 1];
        lo = lo > 0.f ? lo : 0.f;
        hi = hi > 0.f ? hi : 0.f;
        r[2 * p] = (__bf16)lo;
        r[2 * p + 1] = (__bf16)hi;
    }
    return r;
}

template <bool AFF>
__global__ __launch_bounds__(256)
void k_gemm(const ushort* __restrict__ A, const ushort* __restrict__ Wt,
            const float* __restrict__ bias,
            const float* __restrict__ stats_in, const float* __restrict__ gamma,
            const float* __restrict__ beta,
            ushort* __restrict__ C, float* __restrict__ stats_out,
            int n, float inv_n,
            const float* __restrict__ gammaF, const float* __restrict__ betaF,
            float* __restrict__ scale_out, float* __restrict__ shift_out,
            int* __restrict__ ticket) {
    __shared__ ushort WtS[128 * 136];   // row stride 136 ushorts = 272 B
    __shared__ float redS[4][256];      // per-wave col stats staging
    __shared__ float sc_lds[128], sh_lds[128];
    __shared__ int lastS;

    int tid = threadIdx.x;

    // stage Wt (32 KB = 2048 uint4) coalesced
    const uint4* wsrc = (const uint4*)Wt;
    #pragma unroll
    for (int j = 0; j < 8; ++j) {
        int i = tid + j * 256;
        int r = i >> 4, s16 = i & 15;
        *(uint4*)&WtS[r * 136 + s16 * 8] = wsrc[i];
    }
    if (AFF && tid < 128) {
        float s = 0.f, qq = 0.f;
        for (int sl = 0; sl < NSLOT; ++sl) {
            s  += stats_in[sl * 256 + tid];
            qq += stats_in[sl * 256 + 128 + tid];
        }
        float mu  = s * inv_n;
        float var = qq * inv_n - mu * mu;
        var = var < 0.f ? 0.f : var;
        float rs = rsqrtf(var + 1e-5f);
        float sc = gamma[tid] * rs;
        sc_lds[tid] = sc;
        sh_lds[tid] = beta[tid] - mu * sc;
    }

    int wv   = tid >> 6;
    int lane = tid & 63;
    int m16  = lane & 15;
    int kq   = lane >> 4;
    int rowbase = blockIdx.x * 128 + wv * 32;

    // preload raw A bits before the barrier (overlaps Wt staging)
    uint4 zero4; zero4.x = zero4.y = zero4.z = zero4.w = 0u;
    uint4 raw0[4], raw1[4];
    #pragma unroll
    for (int ks = 0; ks < 4; ++ks) {
        int kb = ks * 32 + kq * 8;
        int r0 = rowbase + m16, r1 = rowbase + 16 + m16;
        raw0[ks] = (r0 < n) ? *(const uint4*)&A[(size_t)r0 * D + kb] : zero4;
        raw1[ks] = (r1 < n) ? *(const uint4*)&A[(size_t)r1 * D + kb] : zero4;
    }
    __syncthreads();

    bf16x8 a0[4], a1[4];
    #pragma unroll
    for (int ks = 0; ks < 4; ++ks) {
        int kb = ks * 32 + kq * 8;
        if (AFF) {
            a0[ks] = affine_frag(raw0[ks], kb, sc_lds, sh_lds);
            a1[ks] = affine_frag(raw1[ks], kb, sc_lds, sh_lds);
        } else {
            a0[ks] = *reinterpret_cast<bf16x8*>(&raw0[ks]);
            a1[ks] = *reinterpret_cast<bf16x8*>(&raw1[ks]);
        }
    }

    f32x4 acc0[8], acc1[8];
    #pragma unroll
    for (int t = 0; t < 8; ++t) {
        acc0[t] = (f32x4){0.f, 0.f, 0.f, 0.f};
        acc1[t] = (f32x4){0.f, 0.f, 0.f, 0.f};
    }

    #pragma unroll
    for (int ks = 0; ks < 4; ++ks) {
        #pragma unroll
        for (int t = 0; t < 8; ++t) {
            bf16x8 b = *(const bf16x8*)&WtS[(t * 16 + m16) * 136 + ks * 32 + kq * 8];
            acc0[t] = __builtin_amdgcn_mfma_f32_16x16x32_bf16(a0[ks], b, acc0[t], 0, 0, 0);
            acc1[t] = __builtin_amdgcn_mfma_f32_16x16x32_bf16(a1[ks], b, acc1[t], 0, 0, 0);
        }
    }

    // epilogue: bias, bf16 store, col stats -> LDS
    #pragma unroll
    for (int t = 0; t < 8; ++t) {
        int col = t * 16 + m16;
        float bz = bias[col];
        float s = 0.f, qv = 0.f;
        #pragma unroll
        for (int mt = 0; mt < 2; ++mt) {
            f32x4 v4 = mt ? acc1[t] : acc0[t];
            #pragma unroll
            for (int rr = 0; rr < 4; ++rr) {
                int row = rowbase + mt * 16 + kq * 4 + rr;
                if (row < n) {
                    float v = v4[rr] + bz;
                    C[(size_t)row * D + col] = f2b(v);
                    s += v; qv += v * v;
                }
            }
        }
        s += __shfl_xor(s, 16); qv += __shfl_xor(qv, 16);
        s += __shfl_xor(s, 32); qv += __shfl_xor(qv, 32);
        if (kq == 0) {
            redS[wv][col] = s;
            redS[wv][128 + col] = qv;
        }
    }
    __syncthreads();
    // block-level reduce: one atomic per stat-address per block
    int slot = blockIdx.x & (NSLOT - 1);
    float v = redS[0][tid & 255] + redS[1][tid & 255] + redS[2][tid & 255] + redS[3][tid & 255];
    atomicAdd(&stats_out[slot * 256 + (tid & 255)], v);

    // last-block BN fold (replaces the k_bnparams launch)
    if (scale_out) {
        __threadfence();            // my stats atomics visible device-wide
        __syncthreads();            // all threads of this block committed
        if (tid == 0) lastS = (atomicAdd(ticket, 1) == (int)gridDim.x - 1);
        __syncthreads();
        if (lastS && tid < 128) {   // ticket==N-1 => every block's stats visible
            float s = 0.f, qq = 0.f;
            for (int sl = 0; sl < NSLOT; ++sl) {
                s  += stats_out[sl * 256 + tid];
                qq += stats_out[sl * 256 + 128 + tid];
            }
            float mu  = s * inv_n;
            float var = qq * inv_n - mu * mu;
            var = var < 0.f ? 0.f : var;
            float rs = rsqrtf(var + 1e-5f);
            float sc = gammaF[tid] * rs;
            scale_out[tid] = sc;
            shift_out[tid] = betaF[tid] - mu * sc;
        }
    }
}

// ---------------------------------------------------------------- final BN apply (fp32 out)
__global__ __launch_bounds__(256)
void k_final(const unsigned* __restrict__ z, const float* __restrict__ scale,
             const float* __restrict__ shift, float* __restrict__ outf, int total2) {
    int i = blockIdx.x * 256 + threadIdx.x;  // index of uint2 = 4 bf16
    if (i >= total2) return;
    uint2 u = ((const uint2*)z)[i];
    int c = (i * 4) & (D - 1);
    float4 o;
    o.x = b2f_lo(u.x) * scale[c + 0] + shift[c + 0];
    o.y = b2f_hi(u.x) * scale[c + 1] + shift[c + 1];
    o.z = b2f_lo(u.y) * scale[c + 2] + shift[c + 2];
    o.w = b2f_hi(u.y) * scale[c + 3] + shift[c + 3];
    ((float4*)outf)[i] = o;
}

// ---------------------------------------------------------------- launch
extern "C" void kernel_launch(void* const* d_in, const int* in_sizes, int n_in,
                              void* d_out, int out_size, void* d_ws, size_t ws_size,
                              hipStream_t stream) {
    const float* x   = (const float*)d_in[0];
    const int*   ei  = (const int*)d_in[1];
    const float* W1  = (const float*)d_in[4];
    const float* b1  = (const float*)d_in[5];
    const float* g1  = (const float*)d_in[6];
    const float* be1 = (const float*)d_in[7];
    const float* W2  = (const float*)d_in[8];
    const float* b2  = (const float*)d_in[9];
    const float* g2  = (const float*)d_in[10];
    const float* be2 = (const float*)d_in[11];

    const int* srcI = ei;             // edge_index[0]
    const int* dstI = ei + N_EDGES;   // edge_index[1]

    // workspace layout (~61 MB)
    char* ws = (char*)d_ws;
    unsigned* bufA = (unsigned*)ws; ws += (size_t)N_NODES * 64 * 4 + 65536;
    unsigned* bufB = (unsigned*)ws; ws += (size_t)N_NODES * 64 * 4 + 65536;
    int* csrc    = (int*)ws;   ws += (size_t)N_EDGES * 4;
    int* deg     = (int*)ws;   ws += (size_t)N_NODES * 4;
    int* offs    = (int*)ws;   ws += (size_t)N_NODES * 4;
    int* cursor  = (int*)ws;   ws += (size_t)N_NODES * 4;
    int* bsum    = (int*)ws;   ws += 512;
    int* bcur    = (int*)ws;   ws += 512;
    ushort* Wt1  = (ushort*)ws; ws += 3 * D * D * 2;
    ushort* Wt2  = (ushort*)ws; ws += 3 * D * D * 2;
    float* stats = (float*)ws; ws += 6 * NSLOT * 256 * 4;  // 6 write-once regions
    int* tickets = (int*)ws;   ws += 64;                    // 3 ticket counters
    float* scale2 = (float*)ws; ws += 512;
    float* shift2 = (float*)ws; ws += 512;

    // staging buffer for bucketed edge sort: reuse bufB (dead until x2b)
    unsigned* staged = bufB;

    // ---- weight prep (fp32 -> transposed bf16), single launch ----
    k_wprep<<<dim3(D, 3, 2), D, 0, stream>>>(W1, W2, Wt1, Wt2);

    // ---- CSR build ----
    hipMemsetAsync(deg, 0, (size_t)N_NODES * 4, stream);
    k_hist<<<(N_EDGES + 255) / 256, 256, 0, stream>>>(dstI, deg, N_EDGES);
    int nsb = (N_NODES + 1023) / 1024;  // 98
    k_scan_partial<<<nsb, 256, 0, stream>>>(deg, bsum, N_NODES);
    k_scan_top<<<1, 128, 0, stream>>>(bsum, nsb);
    k_scan_final<<<nsb, 256, 0, stream>>>(deg, bsum, offs, cursor, bcur, N_NODES);
    k_bucket<<<(N_EDGES + EPB - 1) / EPB, 256, 0, stream>>>(srcI, dstI, bcur, staged, N_EDGES);
    k_place<<<dim3(NBKT, 2), 1024, 0, stream>>>(staged, offs, cursor, csrc);

    // x -> bf16 into bufB (staged is dead now)
    k_x2b<<<(N_NODES * 32 + 255) / 256, 256, 0, stream>>>(x, bufB, N_NODES * 32);

    // zero the 6 write-once stats regions and the ticket counters (per replay)
    hipMemsetAsync(stats, 0, (size_t)6 * NSLOT * 256 * 4, stream);
    hipMemsetAsync(tickets, 0, 64, stream);

    const float inv_n = 1.0f / (float)N_NODES;
    int ngemm = (N_NODES + 127) / 128;  // 782
    int nagg  = (N_NODES + 3) / 4;
    int nfin  = (N_NODES * D / 4 + 255) / 256;

    // buffer ping-pong: cur = input to this layer's agg; alt = scratch
    unsigned* cur = bufB;
    unsigned* alt = bufA;

    for (int l = 0; l < NLAYER; ++l) {
        float* st1 = stats + (size_t)(2 * l) * NSLOT * 256;
        float* st2 = stats + (size_t)(2 * l + 1) * NSLOT * 256;
        // agg: cur -> alt.  l>0: BN2-apply+relu of previous layer fused in
        // (scale2/shift2 written by previous layer's gemm2 last block).
        if (l == 0)
            k_agg<false><<<nagg, 256, 0, stream>>>(cur, offs, deg, csrc,
                                                   nullptr, nullptr, alt, N_NODES);
        else
            k_agg<true><<<nagg, 256, 0, stream>>>(cur, offs, deg, csrc,
                                                  scale2, shift2, alt, N_NODES);
        // z1 = alt @ W1 + b1 -> cur (bf16), col stats -> st1
        k_gemm<false><<<ngemm, 256, 0, stream>>>(
            (const ushort*)alt, Wt1 + (size_t)l * D * D, b1 + l * D,
            nullptr, nullptr, nullptr, (ushort*)cur, st1, N_NODES, inv_n,
            nullptr, nullptr, nullptr, nullptr, nullptr);
        // z2 = relu(bn1(z1)) @ W2 + b2 -> alt; BN1 from st1 in prologue;
        // last block folds st2 -> scale2/shift2 (BN2 params for next stage)
        k_gemm<true><<<ngemm, 256, 0, stream>>>(
            (const ushort*)cur, Wt2 + (size_t)l * D * D, b2 + l * D,
            st1, g1 + l * D, be1 + l * D, (ushort*)alt, st2, N_NODES, inv_n,
            g2 + l * D, be2 + l * D, scale2, shift2, &tickets[l]);
        // z2 lives in alt; it is the next layer's agg input
        unsigned* t = cur; cur = alt; alt = t;
    }
    // final BN2 apply (no relu), fp32 out
    k_final<<<nfin, 256, 0, stream>>>(cur, scale2, shift2, (float*)d_out, N_NODES * D / 4);
}

// Round 9
// 793.682 us; speedup vs baseline: 1.1407x; 1.1407x over previous
//
#include <hip/hip_runtime.h>

#define N_NODES 100000
#define N_EDGES 1600000
#define D 128
#define NLAYER 3
#define NSLOT 32

// bucket sort params
#define NBKT 98          // ceil(100000 / 1024) node-buckets of 1024
#define EPB 4096         // edges per block in phase A
#define BCAP 96          // LDS per-bucket capacity (mean ~42/block)

typedef __bf16 bf16x8 __attribute__((ext_vector_type(8)));
typedef float f32x4 __attribute__((ext_vector_type(4)));

__device__ inline ushort f2b(float f) {
    union { float f; unsigned u; } v; v.f = f;
    unsigned u = v.u;
    return (ushort)((u + 0x7FFFu + ((u >> 16) & 1u)) >> 16);  // RNE
}
__device__ inline float b2f_lo(unsigned u) {
    union { unsigned u; float f; } v; v.u = u << 16; return v.f;
}
__device__ inline float b2f_hi(unsigned u) {
    union { unsigned u; float f; } v; v.u = u & 0xFFFF0000u; return v.f;
}

// x fp32 -> packed bf16 (layer-0 agg input): halves layer-0 gather bytes
__global__ __launch_bounds__(256)
void k_x2b(const float* __restrict__ x, unsigned* __restrict__ out, int n4) {
    int i = blockIdx.x * 256 + threadIdx.x;  // float4 index
    if (i >= n4) return;
    float4 v = ((const float4*)x)[i];
    uint2 o;
    o.x = (unsigned)f2b(v.x) | ((unsigned)f2b(v.y) << 16);
    o.y = (unsigned)f2b(v.z) | ((unsigned)f2b(v.w) << 16);
    ((uint2*)out)[i] = o;
}

// ---------------------------------------------------------------- CSR build
// Histogram kept as its OWN kernel: 6250 blocks hide the 1.6M random atomic
// latencies (fusing it into k_bucket's 391-block grid was a 2.4x regression).
__global__ void k_hist(const int* __restrict__ dst, int* __restrict__ deg, int e) {
    int i = blockIdx.x * blockDim.x + threadIdx.x;
    if (i < e) atomicAdd(&deg[dst[i]], 1);
}

__global__ void k_scan_partial(const int* __restrict__ deg, int* __restrict__ bsum, int n) {
    __shared__ int sd[256];
    int tid  = threadIdx.x;
    int base = blockIdx.x * 1024 + tid * 4;
    int s = 0;
    #pragma unroll
    for (int j = 0; j < 4; ++j) {
        int idx = base + j;
        if (idx < n) s += deg[idx];
    }
    sd[tid] = s;
    __syncthreads();
    for (int o = 128; o > 0; o >>= 1) {
        if (tid < o) sd[tid] += sd[tid + o];
        __syncthreads();
    }
    if (tid == 0) bsum[blockIdx.x] = sd[0];
}

__global__ void k_scan_top(int* __restrict__ bsum, int nb) {
    __shared__ int sd[128];
    int tid = threadIdx.x;
    int v = (tid < nb) ? bsum[tid] : 0;
    sd[tid] = v;
    __syncthreads();
    int tot = v;
    for (int o = 1; o < 128; o <<= 1) {
        int t = (tid >= o) ? sd[tid - o] : 0;
        __syncthreads();
        sd[tid] += t;
        __syncthreads();
    }
    if (tid < nb) bsum[tid] = sd[tid] - tot;  // exclusive
}

__global__ void k_scan_final(const int* __restrict__ deg, const int* __restrict__ bofs,
                             int* __restrict__ offs, int* __restrict__ cursor,
                             int* __restrict__ bcur, int n) {
    __shared__ int sd[256];
    int tid  = threadIdx.x;
    int base = blockIdx.x * 1024 + tid * 4;
    int v[4];
    int s = 0;
    #pragma unroll
    for (int j = 0; j < 4; ++j) {
        int idx = base + j;
        v[j] = (idx < n) ? deg[idx] : 0;
        s += v[j];
    }
    sd[tid] = s;
    __syncthreads();
    int own = s;
    for (int o = 1; o < 256; o <<= 1) {
        int t = (tid >= o) ? sd[tid - o] : 0;
        __syncthreads();
        sd[tid] += t;
        __syncthreads();
    }
    int excl = sd[tid] - own + bofs[blockIdx.x];
    #pragma unroll
    for (int j = 0; j < 4; ++j) {
        int idx = base + j;
        if (idx < n) {
            offs[idx] = excl; cursor[idx] = excl;
            if ((idx & 1023) == 0) bcur[idx >> 10] = excl;  // bucket region start
        }
        excl += v[j];
    }
}

// ---------------------------------------------------------------- bucketed edge sort
__global__ __launch_bounds__(256)
void k_bucket(const int* __restrict__ src, const int* __restrict__ dst,
              int* __restrict__ bcur, unsigned* __restrict__ staged, int e) {
    __shared__ unsigned lstage[NBKT * BCAP];
    __shared__ int lcur[NBKT];
    __shared__ int lbase[NBKT];
    int tid = threadIdx.x;
    for (int b = tid; b < NBKT; b += 256) lcur[b] = 0;
    __syncthreads();
    int base = blockIdx.x * EPB;
    for (int k = 0; k < EPB / 256; ++k) {
        int eid = base + k * 256 + tid;
        if (eid < e) {
            int d = dst[eid];
            int s = src[eid];
            int b = d >> 10;
            unsigned packed = ((unsigned)(d & 1023) << 17) | (unsigned)s;
            int p = atomicAdd(&lcur[b], 1);
            if (p < BCAP) {
                lstage[b * BCAP + p] = packed;
            } else {  // overflow fallback (statistically never: cap = 2.3x mean)
                int gp = atomicAdd(&bcur[b], 1);
                staged[gp] = packed;
            }
        }
    }
    __syncthreads();
    if (tid < NBKT) {
        int cnt = min(lcur[tid], BCAP);
        lbase[tid] = atomicAdd(&bcur[tid], cnt);
        lcur[tid] = cnt;
    }
    __syncthreads();
    int wave = tid >> 6, lane = tid & 63;
    for (int b = wave; b < NBKT; b += 4) {
        int cnt = lcur[b], gb = lbase[b];
        for (int j = lane; j < cnt; j += 64)
            staged[gb + j] = lstage[b * BCAP + j];
    }
}

__global__ __launch_bounds__(1024)
void k_place(const unsigned* __restrict__ staged, const int* __restrict__ offs,
             int* __restrict__ cursor, int* __restrict__ csrc) {
    int b = blockIdx.x;
    int start = offs[b << 10];
    int end = (b == NBKT - 1) ? N_EDGES : offs[(b + 1) << 10];
    int nodebase = b << 10;
    for (int i = start + blockIdx.y * 1024 + threadIdx.x; i < end; i += 2048) {
        unsigned p = staged[i];
        int s = (int)(p & 0x1FFFFu);
        int rel = (int)(p >> 17);
        int pos = atomicAdd(&cursor[nodebase + rel], 1);
        csrc[pos] = s;
    }
}

// ---------------------------------------------------------------- aggregation
// out[i,:] = bf16( f(h[i,:]) + sum_j f(h[src_j,:]) ),  f = AFF ? relu(v*sc+sh) : v.
// One wave per node (25000 blocks -> full gather TLP; do NOT fuse with GEMM).
template <bool AFF>
__device__ inline void acc8(float* a, uint4 u, const float* sc, const float* sh) {
    float v[8];
    v[0] = b2f_lo(u.x); v[1] = b2f_hi(u.x);
    v[2] = b2f_lo(u.y); v[3] = b2f_hi(u.y);
    v[4] = b2f_lo(u.z); v[5] = b2f_hi(u.z);
    v[6] = b2f_lo(u.w); v[7] = b2f_hi(u.w);
    #pragma unroll
    for (int j = 0; j < 8; ++j) {
        float t = v[j];
        if (AFF) {
            t = t * sc[j] + sh[j];
            t = t > 0.f ? t : 0.f;
        }
        a[j] += t;
    }
}

template <bool AFF>
__global__ __launch_bounds__(256)
void k_agg(const unsigned* __restrict__ h, const int* __restrict__ offs,
           const int* __restrict__ deg, const int* __restrict__ csrc,
           const float* __restrict__ sc_, const float* __restrict__ sh_,
           unsigned* __restrict__ out, int n) {
    int node = blockIdx.x * 4 + (threadIdx.x >> 6);
    if (node >= n) return;
    int lane = threadIdx.x & 63;
    int q  = lane >> 4;   // neighbor stream j === q (mod 4)
    int sl = lane & 15;   // covers uints 4sl..4sl+3 (cols 8sl..8sl+7)
    const uint4* hp = (const uint4*)h;
    float sc[8], sh[8];
    if (AFF) {
        #pragma unroll
        for (int j = 0; j < 8; ++j) { sc[j] = sc_[sl * 8 + j]; sh[j] = sh_[sl * 8 + j]; }
    }
    float a[8];
    #pragma unroll
    for (int j = 0; j < 8; ++j) a[j] = 0.f;
    if (q == 0) acc8<AFF>(a, hp[(size_t)node * 16 + sl], sc, sh);
    int s = offs[node], d = deg[node];
    for (int c = 0; c < d; c += 64) {
        int m = min(64, d - c);
        int myi = (lane < m) ? csrc[s + c + lane] : 0;
        int g4 = m >> 2;
        int g = 0;
        for (; g + 4 <= g4; g += 4) {
            int n0 = __shfl(myi, 4 * g + 0 + q);
            int n1 = __shfl(myi, 4 * g + 4 + q);
            int n2 = __shfl(myi, 4 * g + 8 + q);
            int n3 = __shfl(myi, 4 * g + 12 + q);
            uint4 u0 = hp[(size_t)n0 * 16 + sl];
            uint4 u1 = hp[(size_t)n1 * 16 + sl];
            uint4 u2 = hp[(size_t)n2 * 16 + sl];
            uint4 u3 = hp[(size_t)n3 * 16 + sl];
            acc8<AFF>(a, u0, sc, sh);
            acc8<AFF>(a, u1, sc, sh);
            acc8<AFF>(a, u2, sc, sh);
            acc8<AFF>(a, u3, sc, sh);
        }
        for (; g < g4; ++g) {
            int nb = __shfl(myi, 4 * g + q);
            acc8<AFF>(a, hp[(size_t)nb * 16 + sl], sc, sh);
        }
        int rem = m & 3;
        if (rem) {
            int j = 4 * g4 + q;
            int nb = __shfl(myi, j < m ? j : 0);  // convergent shfl
            if (q < rem) acc8<AFF>(a, hp[(size_t)nb * 16 + sl], sc, sh);
        }
    }
    #pragma unroll
    for (int j = 0; j < 8; ++j) {
        a[j] += __shfl_xor(a[j], 16);
        a[j] += __shfl_xor(a[j], 32);
    }
    if (q == 0) {
        uint4 o;
        o.x = (unsigned)f2b(a[0]) | ((unsigned)f2b(a[1]) << 16);
        o.y = (unsigned)f2b(a[2]) | ((unsigned)f2b(a[3]) << 16);
        o.z = (unsigned)f2b(a[4]) | ((unsigned)f2b(a[5]) << 16);
        o.w = (unsigned)f2b(a[6]) | ((unsigned)f2b(a[7]) << 16);
        ((uint4*)out)[(size_t)node * 16 + sl] = o;
    }
}

// ---------------------------------------------------------------- weight prep
// Both W1,W2 fp32 [3][k][n] -> transposed bf16 [3][n][k] in ONE launch (z picks).
__global__ void k_wprep(const float* __restrict__ W1, const float* __restrict__ W2,
                        ushort* __restrict__ Wt1, ushort* __restrict__ Wt2) {
    int m = blockIdx.y, nn = blockIdx.x, k = threadIdx.x;
    const float* W = blockIdx.z ? W2 : W1;
    ushort* Wt = blockIdx.z ? Wt2 : Wt1;
    Wt[(m * D + nn) * D + k] = f2b(W[(m * D + k) * D + nn]);
}

// ---------------------------------------------------------------- MFMA GEMM
// AFF=false: C = A @ Wt + bias          (A raw bf16)
// AFF=true : C = relu(bn(A)) @ Wt + bias, bn params computed in prologue.
// B-frags read DIRECT from global: Wt is 32 KB -> L1-resident after first touch
// (8x in-block reuse). No Wt staging => no pre-MFMA barrier for AFF=false,
// LDS 40 KB -> 5 KB (occupancy 4 -> ~6 blocks/CU), no bank conflicts.
// Column stats: per-block LDS reduce -> 256 atomics/block into NSLOT=32 slots.
__device__ inline bf16x8 affine_frag(uint4 raw, int kb,
                                     const float* __restrict__ sc,
                                     const float* __restrict__ sh) {
    unsigned u[4];
    u[0] = raw.x; u[1] = raw.y; u[2] = raw.z; u[3] = raw.w;
    bf16x8 r;
    #pragma unroll
    for (int p = 0; p < 4; ++p) {
        float lo = b2f_lo(u[p]) * sc[kb + 2 * p] + sh[kb + 2 * p];
        float hi = b2f_hi(u[p]) * sc[kb + 2 * p + 1] + sh[kb + 2 * p + 1];
        lo = lo > 0.f ? lo : 0.f;
        hi = hi > 0.f ? hi : 0.f;
        r[2 * p] = (__bf16)lo;
        r[2 * p + 1] = (__bf16)hi;
    }
    return r;
}

template <bool AFF>
__global__ __launch_bounds__(256)
void k_gemm(const ushort* __restrict__ A, const ushort* __restrict__ Wt,
            const float* __restrict__ bias,
            const float* __restrict__ stats_in, const float* __restrict__ gamma,
            const float* __restrict__ beta,
            ushort* __restrict__ C, float* __restrict__ stats_out,
            int n, float inv_n) {
    __shared__ float redS[4][256];      // per-wave col stats staging
    __shared__ float sc_lds[128], sh_lds[128];

    int tid = threadIdx.x;
    if (AFF && tid < 128) {
        float s = 0.f, qq = 0.f;
        for (int sl = 0; sl < NSLOT; ++sl) {
            s  += stats_in[sl * 256 + tid];
            qq += stats_in[sl * 256 + 128 + tid];
        }
        float mu  = s * inv_n;
        float var = qq * inv_n - mu * mu;
        var = var < 0.f ? 0.f : var;
        float rs = rsqrtf(var + 1e-5f);
        float sc = gamma[tid] * rs;
        sc_lds[tid] = sc;
        sh_lds[tid] = beta[tid] - mu * sc;
    }

    int wv   = tid >> 6;
    int lane = tid & 63;
    int m16  = lane & 15;
    int kq   = lane >> 4;
    int rowbase = blockIdx.x * 128 + wv * 32;

    // A-frags: 2 m-tiles x 4 k-steps (raw loads issue before the AFF barrier)
    uint4 zero4; zero4.x = zero4.y = zero4.z = zero4.w = 0u;
    uint4 raw0[4], raw1[4];
    #pragma unroll
    for (int ks = 0; ks < 4; ++ks) {
        int kb = ks * 32 + kq * 8;
        int r0 = rowbase + m16, r1 = rowbase + 16 + m16;
        raw0[ks] = (r0 < n) ? *(const uint4*)&A[(size_t)r0 * D + kb] : zero4;
        raw1[ks] = (r1 < n) ? *(const uint4*)&A[(size_t)r1 * D + kb] : zero4;
    }
    if (AFF) __syncthreads();   // sc_lds/sh_lds ready

    bf16x8 a0[4], a1[4];
    #pragma unroll
    for (int ks = 0; ks < 4; ++ks) {
        int kb = ks * 32 + kq * 8;
        if (AFF) {
            a0[ks] = affine_frag(raw0[ks], kb, sc_lds, sh_lds);
            a1[ks] = affine_frag(raw1[ks], kb, sc_lds, sh_lds);
        } else {
            a0[ks] = *reinterpret_cast<bf16x8*>(&raw0[ks]);
            a1[ks] = *reinterpret_cast<bf16x8*>(&raw1[ks]);
        }
    }

    f32x4 acc0[8], acc1[8];
    #pragma unroll
    for (int t = 0; t < 8; ++t) {
        acc0[t] = (f32x4){0.f, 0.f, 0.f, 0.f};
        acc1[t] = (f32x4){0.f, 0.f, 0.f, 0.f};
    }

    #pragma unroll
    for (int ks = 0; ks < 4; ++ks) {
        int kb = ks * 32 + kq * 8;
        #pragma unroll
        for (int t = 0; t < 8; ++t) {
            bf16x8 b = *(const bf16x8*)&Wt[(size_t)(t * 16 + m16) * D + kb];
            acc0[t] = __builtin_amdgcn_mfma_f32_16x16x32_bf16(a0[ks], b, acc0[t], 0, 0, 0);
            acc1[t] = __builtin_amdgcn_mfma_f32_16x16x32_bf16(a1[ks], b, acc1[t], 0, 0, 0);
        }
    }

    // epilogue: bias, bf16 store, col stats -> LDS
    #pragma unroll
    for (int t = 0; t < 8; ++t) {
        int col = t * 16 + m16;
        float bz = bias[col];
        float s = 0.f, qv = 0.f;
        #pragma unroll
        for (int mt = 0; mt < 2; ++mt) {
            f32x4 v4 = mt ? acc1[t] : acc0[t];
            #pragma unroll
            for (int rr = 0; rr < 4; ++rr) {
                int row = rowbase + mt * 16 + kq * 4 + rr;
                if (row < n) {
                    float v = v4[rr] + bz;
                    C[(size_t)row * D + col] = f2b(v);
                    s += v; qv += v * v;
                }
            }
        }
        s += __shfl_xor(s, 16); qv += __shfl_xor(qv, 16);
        s += __shfl_xor(s, 32); qv += __shfl_xor(qv, 32);
        if (kq == 0) {
            redS[wv][col] = s;
            redS[wv][128 + col] = qv;
        }
    }
    __syncthreads();
    // block-level reduce: one atomic per stat-address per block
    int slot = blockIdx.x & (NSLOT - 1);
    float v = redS[0][tid & 255] + redS[1][tid & 255] + redS[2][tid & 255] + redS[3][tid & 255];
    atomicAdd(&stats_out[slot * 256 + (tid & 255)], v);
}

// ---------------------------------------------------------------- BN param fold
// (BN2 only: consumed by next layer's agg or the final apply.  A 1-block
// launch is ~2us; folding this into k_gemm via device-scope fence was a
// 3x40us regression -- the fence's L2 writeback serialized the whole GPU.)
__global__ void k_bnparams(const float* __restrict__ stats, const float* __restrict__ gamma,
                           const float* __restrict__ beta, float* __restrict__ scale,
                           float* __restrict__ shift, float inv_n) {
    int c = threadIdx.x;  // 128 threads
    float s = 0.f, q = 0.f;
    for (int sl = 0; sl < NSLOT; ++sl) {
        s += stats[sl * 256 + c];
        q += stats[sl * 256 + 128 + c];
    }
    float mu  = s * inv_n;
    float var = q * inv_n - mu * mu;
    var = var < 0.f ? 0.f : var;
    float rs = rsqrtf(var + 1e-5f);
    float sc = gamma[c] * rs;
    scale[c] = sc;
    shift[c] = beta[c] - mu * sc;
}

// ---------------------------------------------------------------- final BN apply (fp32 out)
__global__ __launch_bounds__(256)
void k_final(const unsigned* __restrict__ z, const float* __restrict__ scale,
             const float* __restrict__ shift, float* __restrict__ outf, int total2) {
    int i = blockIdx.x * 256 + threadIdx.x;  // index of uint2 = 4 bf16
    if (i >= total2) return;
    uint2 u = ((const uint2*)z)[i];
    int c = (i * 4) & (D - 1);
    float4 o;
    o.x = b2f_lo(u.x) * scale[c + 0] + shift[c + 0];
    o.y = b2f_hi(u.x) * scale[c + 1] + shift[c + 1];
    o.z = b2f_lo(u.y) * scale[c + 2] + shift[c + 2];
    o.w = b2f_hi(u.y) * scale[c + 3] + shift[c + 3];
    ((float4*)outf)[i] = o;
}

// ---------------------------------------------------------------- launch
extern "C" void kernel_launch(void* const* d_in, const int* in_sizes, int n_in,
                              void* d_out, int out_size, void* d_ws, size_t ws_size,
                              hipStream_t stream) {
    const float* x   = (const float*)d_in[0];
    const int*   ei  = (const int*)d_in[1];
    const float* W1  = (const float*)d_in[4];
    const float* b1  = (const float*)d_in[5];
    const float* g1  = (const float*)d_in[6];
    const float* be1 = (const float*)d_in[7];
    const float* W2  = (const float*)d_in[8];
    const float* b2  = (const float*)d_in[9];
    const float* g2  = (const float*)d_in[10];
    const float* be2 = (const float*)d_in[11];

    const int* srcI = ei;             // edge_index[0]
    const int* dstI = ei + N_EDGES;   // edge_index[1]

    // workspace layout (~61 MB)
    char* ws = (char*)d_ws;
    unsigned* bufA = (unsigned*)ws; ws += (size_t)N_NODES * 64 * 4 + 65536;
    unsigned* bufB = (unsigned*)ws; ws += (size_t)N_NODES * 64 * 4 + 65536;
    int* csrc    = (int*)ws;   ws += (size_t)N_EDGES * 4;
    int* deg     = (int*)ws;   ws += (size_t)N_NODES * 4;
    int* offs    = (int*)ws;   ws += (size_t)N_NODES * 4;
    int* cursor  = (int*)ws;   ws += (size_t)N_NODES * 4;
    int* bsum    = (int*)ws;   ws += 512;
    int* bcur    = (int*)ws;   ws += 512;
    ushort* Wt1  = (ushort*)ws; ws += 3 * D * D * 2;
    ushort* Wt2  = (ushort*)ws; ws += 3 * D * D * 2;
    float* stats = (float*)ws; ws += 6 * NSLOT * 256 * 4;  // 6 write-once regions
    float* scale2 = (float*)ws; ws += 512;
    float* shift2 = (float*)ws; ws += 512;

    // staging buffer for bucketed edge sort: reuse bufB (dead until x2b)
    unsigned* staged = bufB;

    // ---- weight prep (fp32 -> transposed bf16), single launch ----
    k_wprep<<<dim3(D, 3, 2), D, 0, stream>>>(W1, W2, Wt1, Wt2);

    // ---- CSR build ----
    hipMemsetAsync(deg, 0, (size_t)N_NODES * 4, stream);
    k_hist<<<(N_EDGES + 255) / 256, 256, 0, stream>>>(dstI, deg, N_EDGES);
    int nsb = (N_NODES + 1023) / 1024;  // 98
    k_scan_partial<<<nsb, 256, 0, stream>>>(deg, bsum, N_NODES);
    k_scan_top<<<1, 128, 0, stream>>>(bsum, nsb);
    k_scan_final<<<nsb, 256, 0, stream>>>(deg, bsum, offs, cursor, bcur, N_NODES);
    k_bucket<<<(N_EDGES + EPB - 1) / EPB, 256, 0, stream>>>(srcI, dstI, bcur, staged, N_EDGES);
    k_place<<<dim3(NBKT, 2), 1024, 0, stream>>>(staged, offs, cursor, csrc);

    // x -> bf16 into bufB (staged is dead now)
    k_x2b<<<(N_NODES * 32 + 255) / 256, 256, 0, stream>>>(x, bufB, N_NODES * 32);

    // zero the 6 write-once stats regions (per replay)
    hipMemsetAsync(stats, 0, (size_t)6 * NSLOT * 256 * 4, stream);

    const float inv_n = 1.0f / (float)N_NODES;
    int ngemm = (N_NODES + 127) / 128;  // 782
    int nagg  = (N_NODES + 3) / 4;
    int nfin  = (N_NODES * D / 4 + 255) / 256;

    // buffer ping-pong: cur = input to this layer's agg; alt = scratch
    unsigned* cur = bufB;
    unsigned* alt = bufA;

    for (int l = 0; l < NLAYER; ++l) {
        float* st1 = stats + (size_t)(2 * l) * NSLOT * 256;
        float* st2 = stats + (size_t)(2 * l + 1) * NSLOT * 256;
        // agg: cur -> alt.  l>0: BN2-apply+relu of previous layer fused in.
        if (l == 0)
            k_agg<false><<<nagg, 256, 0, stream>>>(cur, offs, deg, csrc,
                                                   nullptr, nullptr, alt, N_NODES);
        else
            k_agg<true><<<nagg, 256, 0, stream>>>(cur, offs, deg, csrc,
                                                  scale2, shift2, alt, N_NODES);
        // z1 = alt @ W1 + b1 -> cur (bf16), col stats -> st1
        k_gemm<false><<<ngemm, 256, 0, stream>>>(
            (const ushort*)alt, Wt1 + (size_t)l * D * D, b1 + l * D,
            nullptr, nullptr, nullptr, (ushort*)cur, st1, N_NODES, inv_n);
        // z2 = relu(bn1(z1)) @ W2 + b2 -> alt (bf16); BN1 from st1 in prologue
        k_gemm<true><<<ngemm, 256, 0, stream>>>(
            (const ushort*)cur, Wt2 + (size_t)l * D * D, b2 + l * D,
            st1, g1 + l * D, be1 + l * D, (ushort*)alt, st2, N_NODES, inv_n);
        // BN2 params for next agg (l<2) or final apply (l=2)
        k_bnparams<<<1, D, 0, stream>>>(st2, g2 + l * D, be2 + l * D,
                                        scale2, shift2, inv_n);
        // z2 lives in alt; it is the next layer's agg input
        unsigned* t = cur; cur = alt; alt = t;
    }
    // final BN2 apply (no relu), fp32 out
    k_final<<<nfin, 256, 0, stream>>>(cur, scale2, shift2, (float*)d_out, N_NODES * D / 4);
}

// Round 10
// 659.822 us; speedup vs baseline: 1.3721x; 1.2029x over previous
//
#include <hip/hip_runtime.h>

#define N_NODES 100000
#define N_EDGES 1600000
#define D 128
#define NLAYER 3
#define NSLOT 32

// bucket sort params
#define NBKT 98          // ceil(100000 / 1024) node-buckets of 1024
#define EPB 4096         // edges per block in phase A
#define BCAP 96          // LDS per-bucket capacity (mean ~42/block)

typedef __bf16 bf16x8 __attribute__((ext_vector_type(8)));
typedef float f32x4 __attribute__((ext_vector_type(4)));

__device__ inline ushort f2b(float f) {
    union { float f; unsigned u; } v; v.f = f;
    unsigned u = v.u;
    return (ushort)((u + 0x7FFFu + ((u >> 16) & 1u)) >> 16);  // RNE
}
__device__ inline float b2f_lo(unsigned u) {
    union { unsigned u; float f; } v; v.u = u << 16; return v.f;
}
__device__ inline float b2f_hi(unsigned u) {
    union { unsigned u; float f; } v; v.u = u & 0xFFFF0000u; return v.f;
}

// x fp32 -> packed bf16 (layer-0 agg input): halves layer-0 gather bytes
__global__ __launch_bounds__(256)
void k_x2b(const float* __restrict__ x, unsigned* __restrict__ out, int n4) {
    int i = blockIdx.x * 256 + threadIdx.x;  // float4 index
    if (i >= n4) return;
    float4 v = ((const float4*)x)[i];
    uint2 o;
    o.x = (unsigned)f2b(v.x) | ((unsigned)f2b(v.y) << 16);
    o.y = (unsigned)f2b(v.z) | ((unsigned)f2b(v.w) << 16);
    ((uint2*)out)[i] = o;
}

// ---------------------------------------------------------------- CSR build
// Histogram kept as its OWN kernel: 6250 blocks hide the 1.6M random atomic
// latencies (fusing it into k_bucket's 391-block grid was a 2.4x regression).
__global__ void k_hist(const int* __restrict__ dst, int* __restrict__ deg, int e) {
    int i = blockIdx.x * blockDim.x + threadIdx.x;
    if (i < e) atomicAdd(&deg[dst[i]], 1);
}

__global__ void k_scan_partial(const int* __restrict__ deg, int* __restrict__ bsum, int n) {
    __shared__ int sd[256];
    int tid  = threadIdx.x;
    int base = blockIdx.x * 1024 + tid * 4;
    int s = 0;
    #pragma unroll
    for (int j = 0; j < 4; ++j) {
        int idx = base + j;
        if (idx < n) s += deg[idx];
    }
    sd[tid] = s;
    __syncthreads();
    for (int o = 128; o > 0; o >>= 1) {
        if (tid < o) sd[tid] += sd[tid + o];
        __syncthreads();
    }
    if (tid == 0) bsum[blockIdx.x] = sd[0];
}

__global__ void k_scan_top(int* __restrict__ bsum, int nb) {
    __shared__ int sd[128];
    int tid = threadIdx.x;
    int v = (tid < nb) ? bsum[tid] : 0;
    sd[tid] = v;
    __syncthreads();
    int tot = v;
    for (int o = 1; o < 128; o <<= 1) {
        int t = (tid >= o) ? sd[tid - o] : 0;
        __syncthreads();
        sd[tid] += t;
        __syncthreads();
    }
    if (tid < nb) bsum[tid] = sd[tid] - tot;  // exclusive
}

__global__ void k_scan_final(const int* __restrict__ deg, const int* __restrict__ bofs,
                             int* __restrict__ offs, int* __restrict__ cursor,
                             int* __restrict__ bcur, int n) {
    __shared__ int sd[256];
    int tid  = threadIdx.x;
    int base = blockIdx.x * 1024 + tid * 4;
    int v[4];
    int s = 0;
    #pragma unroll
    for (int j = 0; j < 4; ++j) {
        int idx = base + j;
        v[j] = (idx < n) ? deg[idx] : 0;
        s += v[j];
    }
    sd[tid] = s;
    __syncthreads();
    int own = s;
    for (int o = 1; o < 256; o <<= 1) {
        int t = (tid >= o) ? sd[tid - o] : 0;
        __syncthreads();
        sd[tid] += t;
        __syncthreads();
    }
    int excl = sd[tid] - own + bofs[blockIdx.x];
    #pragma unroll
    for (int j = 0; j < 4; ++j) {
        int idx = base + j;
        if (idx < n) {
            offs[idx] = excl; cursor[idx] = excl;
            if ((idx & 1023) == 0) bcur[idx >> 10] = excl;  // bucket region start
        }
        excl += v[j];
    }
}

// ---------------------------------------------------------------- bucketed edge sort
__global__ __launch_bounds__(256)
void k_bucket(const int* __restrict__ src, const int* __restrict__ dst,
              int* __restrict__ bcur, unsigned* __restrict__ staged, int e) {
    __shared__ unsigned lstage[NBKT * BCAP];
    __shared__ int lcur[NBKT];
    __shared__ int lbase[NBKT];
    int tid = threadIdx.x;
    for (int b = tid; b < NBKT; b += 256) lcur[b] = 0;
    __syncthreads();
    int base = blockIdx.x * EPB;
    for (int k = 0; k < EPB / 256; ++k) {
        int eid = base + k * 256 + tid;
        if (eid < e) {
            int d = dst[eid];
            int s = src[eid];
            int b = d >> 10;
            unsigned packed = ((unsigned)(d & 1023) << 17) | (unsigned)s;
            int p = atomicAdd(&lcur[b], 1);
            if (p < BCAP) {
                lstage[b * BCAP + p] = packed;
            } else {  // overflow fallback (statistically never: cap = 2.3x mean)
                int gp = atomicAdd(&bcur[b], 1);
                staged[gp] = packed;
            }
        }
    }
    __syncthreads();
    if (tid < NBKT) {
        int cnt = min(lcur[tid], BCAP);
        lbase[tid] = atomicAdd(&bcur[tid], cnt);
        lcur[tid] = cnt;
    }
    __syncthreads();
    int wave = tid >> 6, lane = tid & 63;
    for (int b = wave; b < NBKT; b += 4) {
        int cnt = lcur[b], gb = lbase[b];
        for (int j = lane; j < cnt; j += 64)
            staged[gb + j] = lstage[b * BCAP + j];
    }
}

__global__ __launch_bounds__(1024)
void k_place(const unsigned* __restrict__ staged, const int* __restrict__ offs,
             int* __restrict__ cursor, int* __restrict__ csrc) {
    int b = blockIdx.x;
    int start = offs[b << 10];
    int end = (b == NBKT - 1) ? N_EDGES : offs[(b + 1) << 10];
    int nodebase = b << 10;
    for (int i = start + blockIdx.y * 1024 + threadIdx.x; i < end; i += 2048) {
        unsigned p = staged[i];
        int s = (int)(p & 0x1FFFFu);
        int rel = (int)(p >> 17);
        int pos = atomicAdd(&cursor[nodebase + rel], 1);
        csrc[pos] = s;
    }
}

// ---------------------------------------------------------------- aggregation
// out[i,:] = bf16( f(h[i,:]) + sum_j f(h[src_j,:]) ),  f = AFF ? relu(v*sc+sh) : v.
// One wave per node (25000 blocks -> full gather TLP; do NOT fuse with GEMM).
template <bool AFF>
__device__ inline void acc8(float* a, uint4 u, const float* sc, const float* sh) {
    float v[8];
    v[0] = b2f_lo(u.x); v[1] = b2f_hi(u.x);
    v[2] = b2f_lo(u.y); v[3] = b2f_hi(u.y);
    v[4] = b2f_lo(u.z); v[5] = b2f_hi(u.z);
    v[6] = b2f_lo(u.w); v[7] = b2f_hi(u.w);
    #pragma unroll
    for (int j = 0; j < 8; ++j) {
        float t = v[j];
        if (AFF) {
            t = t * sc[j] + sh[j];
            t = t > 0.f ? t : 0.f;
        }
        a[j] += t;
    }
}

template <bool AFF>
__global__ __launch_bounds__(256)
void k_agg(const unsigned* __restrict__ h, const int* __restrict__ offs,
           const int* __restrict__ deg, const int* __restrict__ csrc,
           const float* __restrict__ sc_, const float* __restrict__ sh_,
           unsigned* __restrict__ out, int n) {
    int node = blockIdx.x * 4 + (threadIdx.x >> 6);
    if (node >= n) return;
    int lane = threadIdx.x & 63;
    int q  = lane >> 4;   // neighbor stream j === q (mod 4)
    int sl = lane & 15;   // covers uints 4sl..4sl+3 (cols 8sl..8sl+7)
    const uint4* hp = (const uint4*)h;
    float sc[8], sh[8];
    if (AFF) {
        #pragma unroll
        for (int j = 0; j < 8; ++j) { sc[j] = sc_[sl * 8 + j]; sh[j] = sh_[sl * 8 + j]; }
    }
    float a[8];
    #pragma unroll
    for (int j = 0; j < 8; ++j) a[j] = 0.f;
    if (q == 0) acc8<AFF>(a, hp[(size_t)node * 16 + sl], sc, sh);
    int s = offs[node], d = deg[node];
    for (int c = 0; c < d; c += 64) {
        int m = min(64, d - c);
        int myi = (lane < m) ? csrc[s + c + lane] : 0;
        int g4 = m >> 2;
        int g = 0;
        for (; g + 4 <= g4; g += 4) {
            int n0 = __shfl(myi, 4 * g + 0 + q);
            int n1 = __shfl(myi, 4 * g + 4 + q);
            int n2 = __shfl(myi, 4 * g + 8 + q);
            int n3 = __shfl(myi, 4 * g + 12 + q);
            uint4 u0 = hp[(size_t)n0 * 16 + sl];
            uint4 u1 = hp[(size_t)n1 * 16 + sl];
            uint4 u2 = hp[(size_t)n2 * 16 + sl];
            uint4 u3 = hp[(size_t)n3 * 16 + sl];
            acc8<AFF>(a, u0, sc, sh);
            acc8<AFF>(a, u1, sc, sh);
            acc8<AFF>(a, u2, sc, sh);
            acc8<AFF>(a, u3, sc, sh);
        }
        for (; g < g4; ++g) {
            int nb = __shfl(myi, 4 * g + q);
            acc8<AFF>(a, hp[(size_t)nb * 16 + sl], sc, sh);
        }
        int rem = m & 3;
        if (rem) {
            int j = 4 * g4 + q;
            int nb = __shfl(myi, j < m ? j : 0);  // convergent shfl
            if (q < rem) acc8<AFF>(a, hp[(size_t)nb * 16 + sl], sc, sh);
        }
    }
    #pragma unroll
    for (int j = 0; j < 8; ++j) {
        a[j] += __shfl_xor(a[j], 16);
        a[j] += __shfl_xor(a[j], 32);
    }
    if (q == 0) {
        uint4 o;
        o.x = (unsigned)f2b(a[0]) | ((unsigned)f2b(a[1]) << 16);
        o.y = (unsigned)f2b(a[2]) | ((unsigned)f2b(a[3]) << 16);
        o.z = (unsigned)f2b(a[4]) | ((unsigned)f2b(a[5]) << 16);
        o.w = (unsigned)f2b(a[6]) | ((unsigned)f2b(a[7]) << 16);
        ((uint4*)out)[(size_t)node * 16 + sl] = o;
    }
}

// ---------------------------------------------------------------- weight prep
// Both W1,W2 fp32 [3][k][n] -> transposed bf16 [3][n][k] in ONE launch (z picks).
__global__ void k_wprep(const float* __restrict__ W1, const float* __restrict__ W2,
                        ushort* __restrict__ Wt1, ushort* __restrict__ Wt2) {
    int m = blockIdx.y, nn = blockIdx.x, k = threadIdx.x;
    const float* W = blockIdx.z ? W2 : W1;
    ushort* Wt = blockIdx.z ? Wt2 : Wt1;
    Wt[(m * D + nn) * D + k] = f2b(W[(m * D + k) * D + nn]);
}

// ---------------------------------------------------------------- MFMA GEMM
// R5 structure (LDS-staged Wt, 128-row blocks -- best measured variant) with a
// vectorized epilogue: C repacked through the dead WtS buffer -> 8 coalesced
// uint4 stores/thread instead of 64 scalar bf16 stores (write-amp fix).
__device__ inline bf16x8 affine_frag(uint4 raw, int kb,
                                     const float* __restrict__ sc,
                                     const float* __restrict__ sh) {
    unsigned u[4];
    u[0] = raw.x; u[1] = raw.y; u[2] = raw.z; u[3] = raw.w;
    bf16x8 r;
    #pragma unroll
    for (int p = 0; p < 4; ++p) {
        float lo = b2f_lo(u[p]) * sc[kb + 2 * p] + sh[kb + 2 * p];
        float hi = b2f_hi(u[p]) * sc[kb + 2 * p + 1] + sh[kb + 2 * p + 1];
        lo = lo > 0.f ? lo : 0.f;
        hi = hi > 0.f ? hi : 0.f;
        r[2 * p] = (__bf16)lo;
        r[2 * p + 1] = (__bf16)hi;
    }
    return r;
}

template <bool AFF>
__global__ __launch_bounds__(256)
void k_gemm(const ushort* __restrict__ A, const ushort* __restrict__ Wt,
            const float* __restrict__ bias,
            const float* __restrict__ stats_in, const float* __restrict__ gamma,
            const float* __restrict__ beta,
            ushort* __restrict__ C, float* __restrict__ stats_out,
            int n, float inv_n) {
    __shared__ ushort WtS[128 * 136];   // Wt stage, then C repack buffer
    __shared__ float redS[4][256];      // per-wave col stats staging
    __shared__ float sc_lds[128], sh_lds[128];

    int tid = threadIdx.x;

    // stage Wt (32 KB = 2048 uint4) coalesced
    const uint4* wsrc = (const uint4*)Wt;
    #pragma unroll
    for (int j = 0; j < 8; ++j) {
        int i = tid + j * 256;
        int r = i >> 4, s16 = i & 15;
        *(uint4*)&WtS[r * 136 + s16 * 8] = wsrc[i];
    }
    if (AFF && tid < 128) {
        float s = 0.f, qq = 0.f;
        for (int sl = 0; sl < NSLOT; ++sl) {
            s  += stats_in[sl * 256 + tid];
            qq += stats_in[sl * 256 + 128 + tid];
        }
        float mu  = s * inv_n;
        float var = qq * inv_n - mu * mu;
        var = var < 0.f ? 0.f : var;
        float rs = rsqrtf(var + 1e-5f);
        float sc = gamma[tid] * rs;
        sc_lds[tid] = sc;
        sh_lds[tid] = beta[tid] - mu * sc;
    }

    int wv   = tid >> 6;
    int lane = tid & 63;
    int m16  = lane & 15;
    int kq   = lane >> 4;
    int rowbase = blockIdx.x * 128 + wv * 32;

    // preload raw A bits before the barrier (overlaps Wt staging)
    uint4 zero4; zero4.x = zero4.y = zero4.z = zero4.w = 0u;
    uint4 raw0[4], raw1[4];
    #pragma unroll
    for (int ks = 0; ks < 4; ++ks) {
        int kb = ks * 32 + kq * 8;
        int r0 = rowbase + m16, r1 = rowbase + 16 + m16;
        raw0[ks] = (r0 < n) ? *(const uint4*)&A[(size_t)r0 * D + kb] : zero4;
        raw1[ks] = (r1 < n) ? *(const uint4*)&A[(size_t)r1 * D + kb] : zero4;
    }
    __syncthreads();

    bf16x8 a0[4], a1[4];
    #pragma unroll
    for (int ks = 0; ks < 4; ++ks) {
        int kb = ks * 32 + kq * 8;
        if (AFF) {
            a0[ks] = affine_frag(raw0[ks], kb, sc_lds, sh_lds);
            a1[ks] = affine_frag(raw1[ks], kb, sc_lds, sh_lds);
        } else {
            a0[ks] = *reinterpret_cast<bf16x8*>(&raw0[ks]);
            a1[ks] = *reinterpret_cast<bf16x8*>(&raw1[ks]);
        }
    }

    f32x4 acc0[8], acc1[8];
    #pragma unroll
    for (int t = 0; t < 8; ++t) {
        acc0[t] = (f32x4){0.f, 0.f, 0.f, 0.f};
        acc1[t] = (f32x4){0.f, 0.f, 0.f, 0.f};
    }

    #pragma unroll
    for (int ks = 0; ks < 4; ++ks) {
        #pragma unroll
        for (int t = 0; t < 8; ++t) {
            bf16x8 b = *(const bf16x8*)&WtS[(t * 16 + m16) * 136 + ks * 32 + kq * 8];
            acc0[t] = __builtin_amdgcn_mfma_f32_16x16x32_bf16(a0[ks], b, acc0[t], 0, 0, 0);
            acc1[t] = __builtin_amdgcn_mfma_f32_16x16x32_bf16(a1[ks], b, acc1[t], 0, 0, 0);
        }
    }
    __syncthreads();   // all WtS B-reads done; WtS becomes the C repack buffer

    // epilogue: bias + bf16 into LDS (repack), col stats via shuffles
    #pragma unroll
    for (int t = 0; t < 8; ++t) {
        int col = t * 16 + m16;
        float bz = bias[col];
        float s = 0.f, qv = 0.f;
        #pragma unroll
        for (int mt = 0; mt < 2; ++mt) {
            f32x4 v4 = mt ? acc1[t] : acc0[t];
            int lr = wv * 32 + mt * 16 + kq * 4;     // local row base
            #pragma unroll
            for (int rr = 0; rr < 4; ++rr) {
                float v = v4[rr] + bz;
                WtS[(lr + rr) * 136 + col] = f2b(v);
                if (rowbase + mt * 16 + kq * 4 + rr < n) { s += v; qv += v * v; }
            }
        }
        s += __shfl_xor(s, 16); qv += __shfl_xor(qv, 16);
        s += __shfl_xor(s, 32); qv += __shfl_xor(qv, 32);
        if (kq == 0) {
            redS[wv][col] = s;
            redS[wv][128 + col] = qv;
        }
    }
    __syncthreads();

    // coalesced C store: 8 uint4 per thread (full 64B-line writes)
    int blk0 = blockIdx.x * 128;
    #pragma unroll
    for (int j = 0; j < 8; ++j) {
        int i = tid + j * 256;
        int r = i >> 4, s16 = i & 15;
        if (blk0 + r < n)
            *(uint4*)&C[(size_t)(blk0 + r) * D + s16 * 8] = *(const uint4*)&WtS[r * 136 + s16 * 8];
    }
    // block-level stats reduce: one atomic per stat-address per block
    int slot = blockIdx.x & (NSLOT - 1);
    float v = redS[0][tid & 255] + redS[1][tid & 255] + redS[2][tid & 255] + redS[3][tid & 255];
    atomicAdd(&stats_out[slot * 256 + (tid & 255)], v);
}

// ---------------------------------------------------------------- BN param fold
// (BN2 only.  1-block launch ~2us; folding into k_gemm via device fence was a
// 3x40us regression -- the fence's L2 writeback serialized the whole GPU.)
__global__ void k_bnparams(const float* __restrict__ stats, const float* __restrict__ gamma,
                           const float* __restrict__ beta, float* __restrict__ scale,
                           float* __restrict__ shift, float inv_n) {
    int c = threadIdx.x;  // 128 threads
    float s = 0.f, q = 0.f;
    for (int sl = 0; sl < NSLOT; ++sl) {
        s += stats[sl * 256 + c];
        q += stats[sl * 256 + 128 + c];
    }
    float mu  = s * inv_n;
    float var = q * inv_n - mu * mu;
    var = var < 0.f ? 0.f : var;
    float rs = rsqrtf(var + 1e-5f);
    float sc = gamma[c] * rs;
    scale[c] = sc;
    shift[c] = beta[c] - mu * sc;
}

// ---------------------------------------------------------------- final BN apply (fp32 out)
__global__ __launch_bounds__(256)
void k_final(const unsigned* __restrict__ z, const float* __restrict__ scale,
             const float* __restrict__ shift, float* __restrict__ outf, int total2) {
    int i = blockIdx.x * 256 + threadIdx.x;  // index of uint2 = 4 bf16
    if (i >= total2) return;
    uint2 u = ((const uint2*)z)[i];
    int c = (i * 4) & (D - 1);
    float4 o;
    o.x = b2f_lo(u.x) * scale[c + 0] + shift[c + 0];
    o.y = b2f_hi(u.x) * scale[c + 1] + shift[c + 1];
    o.z = b2f_lo(u.y) * scale[c + 2] + shift[c + 2];
    o.w = b2f_hi(u.y) * scale[c + 3] + shift[c + 3];
    ((float4*)outf)[i] = o;
}

// ---------------------------------------------------------------- launch
extern "C" void kernel_launch(void* const* d_in, const int* in_sizes, int n_in,
                              void* d_out, int out_size, void* d_ws, size_t ws_size,
                              hipStream_t stream) {
    const float* x   = (const float*)d_in[0];
    const int*   ei  = (const int*)d_in[1];
    const float* W1  = (const float*)d_in[4];
    const float* b1  = (const float*)d_in[5];
    const float* g1  = (const float*)d_in[6];
    const float* be1 = (const float*)d_in[7];
    const float* W2  = (const float*)d_in[8];
    const float* b2  = (const float*)d_in[9];
    const float* g2  = (const float*)d_in[10];
    const float* be2 = (const float*)d_in[11];

    const int* srcI = ei;             // edge_index[0]
    const int* dstI = ei + N_EDGES;   // edge_index[1]

    // workspace layout (~61 MB)
    char* ws = (char*)d_ws;
    unsigned* bufA = (unsigned*)ws; ws += (size_t)N_NODES * 64 * 4 + 65536;
    unsigned* bufB = (unsigned*)ws; ws += (size_t)N_NODES * 64 * 4 + 65536;
    int* csrc    = (int*)ws;   ws += (size_t)N_EDGES * 4;
    int* deg     = (int*)ws;   ws += (size_t)N_NODES * 4;
    int* offs    = (int*)ws;   ws += (size_t)N_NODES * 4;
    int* cursor  = (int*)ws;   ws += (size_t)N_NODES * 4;
    int* bsum    = (int*)ws;   ws += 512;
    int* bcur    = (int*)ws;   ws += 512;
    ushort* Wt1  = (ushort*)ws; ws += 3 * D * D * 2;
    ushort* Wt2  = (ushort*)ws; ws += 3 * D * D * 2;
    float* stats = (float*)ws; ws += 6 * NSLOT * 256 * 4;  // 6 write-once regions
    float* scale2 = (float*)ws; ws += 512;
    float* shift2 = (float*)ws; ws += 512;

    // staging buffer for bucketed edge sort: reuse bufB (dead until x2b)
    unsigned* staged = bufB;

    // ---- weight prep (fp32 -> transposed bf16), single launch ----
    k_wprep<<<dim3(D, 3, 2), D, 0, stream>>>(W1, W2, Wt1, Wt2);

    // ---- CSR build ----
    hipMemsetAsync(deg, 0, (size_t)N_NODES * 4, stream);
    k_hist<<<(N_EDGES + 255) / 256, 256, 0, stream>>>(dstI, deg, N_EDGES);
    int nsb = (N_NODES + 1023) / 1024;  // 98
    k_scan_partial<<<nsb, 256, 0, stream>>>(deg, bsum, N_NODES);
    k_scan_top<<<1, 128, 0, stream>>>(bsum, nsb);
    k_scan_final<<<nsb, 256, 0, stream>>>(deg, bsum, offs, cursor, bcur, N_NODES);
    k_bucket<<<(N_EDGES + EPB - 1) / EPB, 256, 0, stream>>>(srcI, dstI, bcur, staged, N_EDGES);
    k_place<<<dim3(NBKT, 2), 1024, 0, stream>>>(staged, offs, cursor, csrc);

    // x -> bf16 into bufB (staged is dead now)
    k_x2b<<<(N_NODES * 32 + 255) / 256, 256, 0, stream>>>(x, bufB, N_NODES * 32);

    // zero the 6 write-once stats regions (per replay)
    hipMemsetAsync(stats, 0, (size_t)6 * NSLOT * 256 * 4, stream);

    const float inv_n = 1.0f / (float)N_NODES;
    int ngemm = (N_NODES + 127) / 128;  // 782
    int nagg  = (N_NODES + 3) / 4;
    int nfin  = (N_NODES * D / 4 + 255) / 256;

    // buffer ping-pong: cur = input to this layer's agg; alt = scratch
    unsigned* cur = bufB;
    unsigned* alt = bufA;

    for (int l = 0; l < NLAYER; ++l) {
        float* st1 = stats + (size_t)(2 * l) * NSLOT * 256;
        float* st2 = stats + (size_t)(2 * l + 1) * NSLOT * 256;
        // agg: cur -> alt.  l>0: BN2-apply+relu of previous layer fused in.
        if (l == 0)
            k_agg<false><<<nagg, 256, 0, stream>>>(cur, offs, deg, csrc,
                                                   nullptr, nullptr, alt, N_NODES);
        else
            k_agg<true><<<nagg, 256, 0, stream>>>(cur, offs, deg, csrc,
                                                  scale2, shift2, alt, N_NODES);
        // z1 = alt @ W1 + b1 -> cur (bf16), col stats -> st1
        k_gemm<false><<<ngemm, 256, 0, stream>>>(
            (const ushort*)alt, Wt1 + (size_t)l * D * D, b1 + l * D,
            nullptr, nullptr, nullptr, (ushort*)cur, st1, N_NODES, inv_n);
        // z2 = relu(bn1(z1)) @ W2 + b2 -> alt (bf16); BN1 from st1 in prologue
        k_gemm<true><<<ngemm, 256, 0, stream>>>(
            (const ushort*)cur, Wt2 + (size_t)l * D * D, b2 + l * D,
            st1, g1 + l * D, be1 + l * D, (ushort*)alt, st2, N_NODES, inv_n);
        // BN2 params for next agg (l<2) or final apply (l=2)
        k_bnparams<<<1, D, 0, stream>>>(st2, g2 + l * D, be2 + l * D,
                                        scale2, shift2, inv_n);
        // z2 lives in alt; it is the next layer's agg input
        unsigned* t = cur; cur = alt; alt = t;
    }
    // final BN2 apply (no relu), fp32 out
    k_final<<<nfin, 256, 0, stream>>>(cur, scale2, shift2, (float*)d_out, N_NODES * D / 4);
}

// Round 11
// 556.396 us; speedup vs baseline: 1.6271x; 1.1859x over previous
//
#include <hip/hip_runtime.h>

#define N_NODES 100000
#define N_EDGES 1600000
#define D 128
#define NLAYER 3
#define NSLOT 32

// bucket sort params
#define NBKT 98          // ceil(100000 / 1024) node-buckets of 1024
#define EPB 4096         // edges per block in phase A
#define BCAP 96          // LDS per-bucket capacity in k_bucket (mean ~42/block)
#define BKCAP 18432      // fixed staged/csrc capacity per bucket (mean 16384 + 16 sigma)

typedef __bf16 bf16x8 __attribute__((ext_vector_type(8)));
typedef float f32x4 __attribute__((ext_vector_type(4)));

__device__ inline ushort f2b(float f) {
    union { float f; unsigned u; } v; v.f = f;
    unsigned u = v.u;
    return (ushort)((u + 0x7FFFu + ((u >> 16) & 1u)) >> 16);  // RNE
}
__device__ inline float b2f_lo(unsigned u) {
    union { unsigned u; float f; } v; v.u = u << 16; return v.f;
}
__device__ inline float b2f_hi(unsigned u) {
    union { unsigned u; float f; } v; v.u = u & 0xFFFF0000u; return v.f;
}

// x fp32 -> packed bf16 (layer-0 agg input): halves layer-0 gather bytes
__global__ __launch_bounds__(256)
void k_x2b(const float* __restrict__ x, unsigned* __restrict__ out, int n4) {
    int i = blockIdx.x * 256 + threadIdx.x;  // float4 index
    if (i >= n4) return;
    float4 v = ((const float4*)x)[i];
    uint2 o;
    o.x = (unsigned)f2b(v.x) | ((unsigned)f2b(v.y) << 16);
    o.y = (unsigned)f2b(v.z) | ((unsigned)f2b(v.w) << 16);
    ((uint2*)out)[i] = o;
}

// ---------------------------------------------------------------- bucketed edge sort
// Phase A: stage packed (rel,src) per dst-bucket into FIXED per-bucket regions
// (b*BKCAP + cursor).  No dependency on any prefix scan.
__global__ __launch_bounds__(256)
void k_bucket(const int* __restrict__ src, const int* __restrict__ dst,
              int* __restrict__ bkcnt, unsigned* __restrict__ staged, int e) {
    __shared__ unsigned lstage[NBKT * BCAP];
    __shared__ int lcur[NBKT];
    __shared__ int lbase[NBKT];
    int tid = threadIdx.x;
    for (int b = tid; b < NBKT; b += 256) lcur[b] = 0;
    __syncthreads();
    int base = blockIdx.x * EPB;
    for (int k = 0; k < EPB / 256; ++k) {
        int eid = base + k * 256 + tid;
        if (eid < e) {
            int d = dst[eid];
            int s = src[eid];
            int b = d >> 10;
            unsigned packed = ((unsigned)(d & 1023) << 17) | (unsigned)s;
            int p = atomicAdd(&lcur[b], 1);
            if (p < BCAP) {
                lstage[b * BCAP + p] = packed;
            } else {  // overflow fallback (statistically never: cap = 2.3x mean)
                int gp = atomicAdd(&bkcnt[b], 1);
                if (gp < BKCAP) staged[(size_t)b * BKCAP + gp] = packed;
            }
        }
    }
    __syncthreads();
    if (tid < NBKT) {
        int cnt = min(lcur[tid], BCAP);
        int lb = atomicAdd(&bkcnt[tid], cnt);
        lbase[tid] = lb;
        lcur[tid] = min(cnt, BKCAP - lb);  // defensive clip (never triggers)
    }
    __syncthreads();
    int wave = tid >> 6, lane = tid & 63;
    for (int b = wave; b < NBKT; b += 4) {
        int cnt = lcur[b];
        unsigned* gb = staged + (size_t)b * BKCAP + lbase[b];
        for (int j = lane; j < cnt; j += 64)
            gb[j] = lstage[b * BCAP + j];
    }
}

// Phase B: per-bucket LOCAL CSR build entirely in LDS (replaces the global
// histogram kernel, 3 scan kernels, and the global-atomic place kernel).
// offs[] points into SPARSE per-bucket csrc regions -- agg doesn't need dense.
// All random ops are LDS atomics; global traffic is one bucket's ~72KB window.
__global__ __launch_bounds__(1024)
void k_csr(const unsigned* __restrict__ staged, const int* __restrict__ bkcnt,
           int* __restrict__ deg, int* __restrict__ offs, int* __restrict__ csrc) {
    __shared__ int lhist[1024];
    __shared__ int lexc[1024];
    __shared__ int lcur[1024];
    __shared__ int wsum[16], wexc[16];

    int b   = blockIdx.x;
    int tid = threadIdx.x;
    int lane = tid & 63, w = tid >> 6;
    int cnt = min(bkcnt[b], BKCAP);
    const unsigned* sp = staged + (size_t)b * BKCAP;

    lhist[tid] = 0;
    __syncthreads();
    for (int i = tid; i < cnt; i += 1024)
        atomicAdd(&lhist[sp[i] >> 17], 1);
    __syncthreads();

    // exclusive scan of lhist[1024]: wave-level inclusive shfl scan + wave sums
    int v = lhist[tid];
    int inc = v;
    #pragma unroll
    for (int o = 1; o < 64; o <<= 1) {
        int t = __shfl_up(inc, o);
        if (lane >= o) inc += t;
    }
    if (lane == 63) wsum[w] = inc;
    __syncthreads();
    if (tid < 16) {
        int s = wsum[tid];
        int i2 = s;
        #pragma unroll
        for (int o = 1; o < 16; o <<= 1) {
            int t = __shfl_up(i2, o, 16);
            if ((tid & 15) >= o) i2 += t;
        }
        wexc[tid] = i2 - s;
    }
    __syncthreads();
    int exc = inc - v + wexc[w];
    lexc[tid] = exc;
    int node = (b << 10) + tid;
    if (node < N_NODES) {
        deg[node]  = v;
        offs[node] = b * BKCAP + exc;
    }
    lcur[tid] = 0;
    __syncthreads();

    // place: LDS cursor per node (no global atomics)
    for (int i = tid; i < cnt; i += 1024) {
        unsigned p = sp[i];
        int rel = (int)(p >> 17);
        int k = atomicAdd(&lcur[rel], 1);
        csrc[(size_t)b * BKCAP + lexc[rel] + k] = (int)(p & 0x1FFFFu);
    }
}

// ---------------------------------------------------------------- aggregation
// out[i,:] = bf16( f(h[i,:]) + sum_j f(h[src_j,:]) ),  f = AFF ? relu(v*sc+sh) : v.
// One wave per node (25000 blocks -> full gather TLP; do NOT fuse with GEMM).
template <bool AFF>
__device__ inline void acc8(float* a, uint4 u, const float* sc, const float* sh) {
    float v[8];
    v[0] = b2f_lo(u.x); v[1] = b2f_hi(u.x);
    v[2] = b2f_lo(u.y); v[3] = b2f_hi(u.y);
    v[4] = b2f_lo(u.z); v[5] = b2f_hi(u.z);
    v[6] = b2f_lo(u.w); v[7] = b2f_hi(u.w);
    #pragma unroll
    for (int j = 0; j < 8; ++j) {
        float t = v[j];
        if (AFF) {
            t = t * sc[j] + sh[j];
            t = t > 0.f ? t : 0.f;
        }
        a[j] += t;
    }
}

template <bool AFF>
__global__ __launch_bounds__(256)
void k_agg(const unsigned* __restrict__ h, const int* __restrict__ offs,
           const int* __restrict__ deg, const int* __restrict__ csrc,
           const float* __restrict__ sc_, const float* __restrict__ sh_,
           unsigned* __restrict__ out, int n) {
    int node = blockIdx.x * 4 + (threadIdx.x >> 6);
    if (node >= n) return;
    int lane = threadIdx.x & 63;
    int q  = lane >> 4;   // neighbor stream j === q (mod 4)
    int sl = lane & 15;   // covers uints 4sl..4sl+3 (cols 8sl..8sl+7)
    const uint4* hp = (const uint4*)h;
    float sc[8], sh[8];
    if (AFF) {
        #pragma unroll
        for (int j = 0; j < 8; ++j) { sc[j] = sc_[sl * 8 + j]; sh[j] = sh_[sl * 8 + j]; }
    }
    float a[8];
    #pragma unroll
    for (int j = 0; j < 8; ++j) a[j] = 0.f;
    if (q == 0) acc8<AFF>(a, hp[(size_t)node * 16 + sl], sc, sh);
    int s = offs[node], d = deg[node];
    for (int c = 0; c < d; c += 64) {
        int m = min(64, d - c);
        int myi = (lane < m) ? csrc[s + c + lane] : 0;
        int g4 = m >> 2;
        int g = 0;
        for (; g + 4 <= g4; g += 4) {
            int n0 = __shfl(myi, 4 * g + 0 + q);
            int n1 = __shfl(myi, 4 * g + 4 + q);
            int n2 = __shfl(myi, 4 * g + 8 + q);
            int n3 = __shfl(myi, 4 * g + 12 + q);
            uint4 u0 = hp[(size_t)n0 * 16 + sl];
            uint4 u1 = hp[(size_t)n1 * 16 + sl];
            uint4 u2 = hp[(size_t)n2 * 16 + sl];
            uint4 u3 = hp[(size_t)n3 * 16 + sl];
            acc8<AFF>(a, u0, sc, sh);
            acc8<AFF>(a, u1, sc, sh);
            acc8<AFF>(a, u2, sc, sh);
            acc8<AFF>(a, u3, sc, sh);
        }
        for (; g < g4; ++g) {
            int nb = __shfl(myi, 4 * g + q);
            acc8<AFF>(a, hp[(size_t)nb * 16 + sl], sc, sh);
        }
        int rem = m & 3;
        if (rem) {
            int j = 4 * g4 + q;
            int nb = __shfl(myi, j < m ? j : 0);  // convergent shfl
            if (q < rem) acc8<AFF>(a, hp[(size_t)nb * 16 + sl], sc, sh);
        }
    }
    #pragma unroll
    for (int j = 0; j < 8; ++j) {
        a[j] += __shfl_xor(a[j], 16);
        a[j] += __shfl_xor(a[j], 32);
    }
    if (q == 0) {
        uint4 o;
        o.x = (unsigned)f2b(a[0]) | ((unsigned)f2b(a[1]) << 16);
        o.y = (unsigned)f2b(a[2]) | ((unsigned)f2b(a[3]) << 16);
        o.z = (unsigned)f2b(a[4]) | ((unsigned)f2b(a[5]) << 16);
        o.w = (unsigned)f2b(a[6]) | ((unsigned)f2b(a[7]) << 16);
        ((uint4*)out)[(size_t)node * 16 + sl] = o;
    }
}

// ---------------------------------------------------------------- weight prep
// Both W1,W2 fp32 [3][k][n] -> transposed bf16 [3][n][k] in ONE launch (z picks).
__global__ void k_wprep(const float* __restrict__ W1, const float* __restrict__ W2,
                        ushort* __restrict__ Wt1, ushort* __restrict__ Wt2) {
    int m = blockIdx.y, nn = blockIdx.x, k = threadIdx.x;
    const float* W = blockIdx.z ? W2 : W1;
    ushort* Wt = blockIdx.z ? Wt2 : Wt1;
    Wt[(m * D + nn) * D + k] = f2b(W[(m * D + k) * D + nn]);
}

// ---------------------------------------------------------------- MFMA GEMM
// LDS-staged Wt, 128-row blocks (best measured variant), vectorized epilogue:
// C repacked through the dead WtS buffer -> 8 coalesced uint4 stores/thread.
__device__ inline bf16x8 affine_frag(uint4 raw, int kb,
                                     const float* __restrict__ sc,
                                     const float* __restrict__ sh) {
    unsigned u[4];
    u[0] = raw.x; u[1] = raw.y; u[2] = raw.z; u[3] = raw.w;
    bf16x8 r;
    #pragma unroll
    for (int p = 0; p < 4; ++p) {
        float lo = b2f_lo(u[p]) * sc[kb + 2 * p] + sh[kb + 2 * p];
        float hi = b2f_hi(u[p]) * sc[kb + 2 * p + 1] + sh[kb + 2 * p + 1];
        lo = lo > 0.f ? lo : 0.f;
        hi = hi > 0.f ? hi : 0.f;
        r[2 * p] = (__bf16)lo;
        r[2 * p + 1] = (__bf16)hi;
    }
    return r;
}

template <bool AFF>
__global__ __launch_bounds__(256)
void k_gemm(const ushort* __restrict__ A, const ushort* __restrict__ Wt,
            const float* __restrict__ bias,
            const float* __restrict__ stats_in, const float* __restrict__ gamma,
            const float* __restrict__ beta,
            ushort* __restrict__ C, float* __restrict__ stats_out,
            int n, float inv_n) {
    __shared__ ushort WtS[128 * 136];   // Wt stage, then C repack buffer
    __shared__ float redS[4][256];      // per-wave col stats staging
    __shared__ float sc_lds[128], sh_lds[128];

    int tid = threadIdx.x;

    // stage Wt (32 KB = 2048 uint4) coalesced
    const uint4* wsrc = (const uint4*)Wt;
    #pragma unroll
    for (int j = 0; j < 8; ++j) {
        int i = tid + j * 256;
        int r = i >> 4, s16 = i & 15;
        *(uint4*)&WtS[r * 136 + s16 * 8] = wsrc[i];
    }
    if (AFF && tid < 128) {
        float s = 0.f, qq = 0.f;
        for (int sl = 0; sl < NSLOT; ++sl) {
            s  += stats_in[sl * 256 + tid];
            qq += stats_in[sl * 256 + 128 + tid];
        }
        float mu  = s * inv_n;
        float var = qq * inv_n - mu * mu;
        var = var < 0.f ? 0.f : var;
        float rs = rsqrtf(var + 1e-5f);
        float sc = gamma[tid] * rs;
        sc_lds[tid] = sc;
        sh_lds[tid] = beta[tid] - mu * sc;
    }

    int wv   = tid >> 6;
    int lane = tid & 63;
    int m16  = lane & 15;
    int kq   = lane >> 4;
    int rowbase = blockIdx.x * 128 + wv * 32;

    // preload raw A bits before the barrier (overlaps Wt staging)
    uint4 zero4; zero4.x = zero4.y = zero4.z = zero4.w = 0u;
    uint4 raw0[4], raw1[4];
    #pragma unroll
    for (int ks = 0; ks < 4; ++ks) {
        int kb = ks * 32 + kq * 8;
        int r0 = rowbase + m16, r1 = rowbase + 16 + m16;
        raw0[ks] = (r0 < n) ? *(const uint4*)&A[(size_t)r0 * D + kb] : zero4;
        raw1[ks] = (r1 < n) ? *(const uint4*)&A[(size_t)r1 * D + kb] : zero4;
    }
    __syncthreads();

    bf16x8 a0[4], a1[4];
    #pragma unroll
    for (int ks = 0; ks < 4; ++ks) {
        int kb = ks * 32 + kq * 8;
        if (AFF) {
            a0[ks] = affine_frag(raw0[ks], kb, sc_lds, sh_lds);
            a1[ks] = affine_frag(raw1[ks], kb, sc_lds, sh_lds);
        } else {
            a0[ks] = *reinterpret_cast<bf16x8*>(&raw0[ks]);
            a1[ks] = *reinterpret_cast<bf16x8*>(&raw1[ks]);
        }
    }

    f32x4 acc0[8], acc1[8];
    #pragma unroll
    for (int t = 0; t < 8; ++t) {
        acc0[t] = (f32x4){0.f, 0.f, 0.f, 0.f};
        acc1[t] = (f32x4){0.f, 0.f, 0.f, 0.f};
    }

    #pragma unroll
    for (int ks = 0; ks < 4; ++ks) {
        #pragma unroll
        for (int t = 0; t < 8; ++t) {
            bf16x8 b = *(const bf16x8*)&WtS[(t * 16 + m16) * 136 + ks * 32 + kq * 8];
            acc0[t] = __builtin_amdgcn_mfma_f32_16x16x32_bf16(a0[ks], b, acc0[t], 0, 0, 0);
            acc1[t] = __builtin_amdgcn_mfma_f32_16x16x32_bf16(a1[ks], b, acc1[t], 0, 0, 0);
        }
    }
    __syncthreads();   // all WtS B-reads done; WtS becomes the C repack buffer

    // epilogue: bias + bf16 into LDS (repack), col stats via shuffles
    #pragma unroll
    for (int t = 0; t < 8; ++t) {
        int col = t * 16 + m16;
        float bz = bias[col];
        float s = 0.f, qv = 0.f;
        #pragma unroll
        for (int mt = 0; mt < 2; ++mt) {
            f32x4 v4 = mt ? acc1[t] : acc0[t];
            int lr = wv * 32 + mt * 16 + kq * 4;     // local row base
            #pragma unroll
            for (int rr = 0; rr < 4; ++rr) {
                float v = v4[rr] + bz;
                WtS[(lr + rr) * 136 + col] = f2b(v);
                if (rowbase + mt * 16 + kq * 4 + rr < n) { s += v; qv += v * v; }
            }
        }
        s += __shfl_xor(s, 16); qv += __shfl_xor(qv, 16);
        s += __shfl_xor(s, 32); qv += __shfl_xor(qv, 32);
        if (kq == 0) {
            redS[wv][col] = s;
            redS[wv][128 + col] = qv;
        }
    }
    __syncthreads();

    // coalesced C store: 8 uint4 per thread (full 64B-line writes)
    int blk0 = blockIdx.x * 128;
    #pragma unroll
    for (int j = 0; j < 8; ++j) {
        int i = tid + j * 256;
        int r = i >> 4, s16 = i & 15;
        if (blk0 + r < n)
            *(uint4*)&C[(size_t)(blk0 + r) * D + s16 * 8] = *(const uint4*)&WtS[r * 136 + s16 * 8];
    }
    // block-level stats reduce: one atomic per stat-address per block
    int slot = blockIdx.x & (NSLOT - 1);
    float v = redS[0][tid & 255] + redS[1][tid & 255] + redS[2][tid & 255] + redS[3][tid & 255];
    atomicAdd(&stats_out[slot * 256 + (tid & 255)], v);
}

// ---------------------------------------------------------------- BN param fold
// (BN2 only.  1-block launch ~2us; folding into k_gemm via device fence was a
// 3x40us regression -- the fence's L2 writeback serialized the whole GPU.)
__global__ void k_bnparams(const float* __restrict__ stats, const float* __restrict__ gamma,
                           const float* __restrict__ beta, float* __restrict__ scale,
                           float* __restrict__ shift, float inv_n) {
    int c = threadIdx.x;  // 128 threads
    float s = 0.f, q = 0.f;
    for (int sl = 0; sl < NSLOT; ++sl) {
        s += stats[sl * 256 + c];
        q += stats[sl * 256 + 128 + c];
    }
    float mu  = s * inv_n;
    float var = q * inv_n - mu * mu;
    var = var < 0.f ? 0.f : var;
    float rs = rsqrtf(var + 1e-5f);
    float sc = gamma[c] * rs;
    scale[c] = sc;
    shift[c] = beta[c] - mu * sc;
}

// ---------------------------------------------------------------- final BN apply (fp32 out)
__global__ __launch_bounds__(256)
void k_final(const unsigned* __restrict__ z, const float* __restrict__ scale,
             const float* __restrict__ shift, float* __restrict__ outf, int total2) {
    int i = blockIdx.x * 256 + threadIdx.x;  // index of uint2 = 4 bf16
    if (i >= total2) return;
    uint2 u = ((const uint2*)z)[i];
    int c = (i * 4) & (D - 1);
    float4 o;
    o.x = b2f_lo(u.x) * scale[c + 0] + shift[c + 0];
    o.y = b2f_hi(u.x) * scale[c + 1] + shift[c + 1];
    o.z = b2f_lo(u.y) * scale[c + 2] + shift[c + 2];
    o.w = b2f_hi(u.y) * scale[c + 3] + shift[c + 3];
    ((float4*)outf)[i] = o;
}

// ---------------------------------------------------------------- launch
extern "C" void kernel_launch(void* const* d_in, const int* in_sizes, int n_in,
                              void* d_out, int out_size, void* d_ws, size_t ws_size,
                              hipStream_t stream) {
    const float* x   = (const float*)d_in[0];
    const int*   ei  = (const int*)d_in[1];
    const float* W1  = (const float*)d_in[4];
    const float* b1  = (const float*)d_in[5];
    const float* g1  = (const float*)d_in[6];
    const float* be1 = (const float*)d_in[7];
    const float* W2  = (const float*)d_in[8];
    const float* b2  = (const float*)d_in[9];
    const float* g2  = (const float*)d_in[10];
    const float* be2 = (const float*)d_in[11];

    const int* srcI = ei;             // edge_index[0]
    const int* dstI = ei + N_EDGES;   // edge_index[1]

    // workspace layout (~62 MB)
    char* ws = (char*)d_ws;
    unsigned* bufA = (unsigned*)ws; ws += (size_t)N_NODES * 64 * 4 + 65536;
    unsigned* bufB = (unsigned*)ws; ws += (size_t)N_NODES * 64 * 4 + 65536;
    int* csrc    = (int*)ws;   ws += (size_t)NBKT * BKCAP * 4;   // sparse per-bucket CSR
    int* deg     = (int*)ws;   ws += (size_t)N_NODES * 4;
    int* offs    = (int*)ws;   ws += (size_t)N_NODES * 4;
    int* bkcnt   = (int*)ws;   ws += 512;
    ushort* Wt1  = (ushort*)ws; ws += 3 * D * D * 2;
    ushort* Wt2  = (ushort*)ws; ws += 3 * D * D * 2;
    float* stats = (float*)ws; ws += 6 * NSLOT * 256 * 4;  // 6 write-once regions
    float* scale2 = (float*)ws; ws += 512;
    float* shift2 = (float*)ws; ws += 512;

    // staging buffer for bucketed edge sort: reuse bufB (7.2 MB, dead until x2b)
    unsigned* staged = bufB;

    // ---- weight prep (fp32 -> transposed bf16), single launch ----
    k_wprep<<<dim3(D, 3, 2), D, 0, stream>>>(W1, W2, Wt1, Wt2);

    // ---- CSR build: bucket (fixed regions) -> per-bucket local CSR ----
    hipMemsetAsync(bkcnt, 0, 512, stream);
    k_bucket<<<(N_EDGES + EPB - 1) / EPB, 256, 0, stream>>>(srcI, dstI, bkcnt, staged, N_EDGES);
    k_csr<<<NBKT, 1024, 0, stream>>>(staged, bkcnt, deg, offs, csrc);

    // x -> bf16 into bufB (staged is dead now)
    k_x2b<<<(N_NODES * 32 + 255) / 256, 256, 0, stream>>>(x, bufB, N_NODES * 32);

    // zero the 6 write-once stats regions (per replay)
    hipMemsetAsync(stats, 0, (size_t)6 * NSLOT * 256 * 4, stream);

    const float inv_n = 1.0f / (float)N_NODES;
    int ngemm = (N_NODES + 127) / 128;  // 782
    int nagg  = (N_NODES + 3) / 4;
    int nfin  = (N_NODES * D / 4 + 255) / 256;

    // buffer ping-pong: cur = input to this layer's agg; alt = scratch
    unsigned* cur = bufB;
    unsigned* alt = bufA;

    for (int l = 0; l < NLAYER; ++l) {
        float* st1 = stats + (size_t)(2 * l) * NSLOT * 256;
        float* st2 = stats + (size_t)(2 * l + 1) * NSLOT * 256;
        // agg: cur -> alt.  l>0: BN2-apply+relu of previous layer fused in.
        if (l == 0)
            k_agg<false><<<nagg, 256, 0, stream>>>(cur, offs, deg, csrc,
                                                   nullptr, nullptr, alt, N_NODES);
        else
            k_agg<true><<<nagg, 256, 0, stream>>>(cur, offs, deg, csrc,
                                                  scale2, shift2, alt, N_NODES);
        // z1 = alt @ W1 + b1 -> cur (bf16), col stats -> st1
        k_gemm<false><<<ngemm, 256, 0, stream>>>(
            (const ushort*)alt, Wt1 + (size_t)l * D * D, b1 + l * D,
            nullptr, nullptr, nullptr, (ushort*)cur, st1, N_NODES, inv_n);
        // z2 = relu(bn1(z1)) @ W2 + b2 -> alt (bf16); BN1 from st1 in prologue
        k_gemm<true><<<ngemm, 256, 0, stream>>>(
            (const ushort*)cur, Wt2 + (size_t)l * D * D, b2 + l * D,
            st1, g1 + l * D, be1 + l * D, (ushort*)alt, st2, N_NODES, inv_n);
        // BN2 params for next agg (l<2) or final apply (l=2)
        k_bnparams<<<1, D, 0, stream>>>(st2, g2 + l * D, be2 + l * D,
                                        scale2, shift2, inv_n);
        // z2 lives in alt; it is the next layer's agg input
        unsigned* t = cur; cur = alt; alt = t;
    }
    // final BN2 apply (no relu), fp32 out
    k_final<<<nfin, 256, 0, stream>>>(cur, scale2, shift2, (float*)d_out, N_NODES * D / 4);
}